// Round 1
// baseline (1020.944 us; speedup 1.0000x reference)
//
#include <hip/hip_runtime.h>
#include <math.h>

#define BB 2
#define LL 1024
#define DD 512
#define DIN 1024      // d_inner
#define NS 16         // d_state
#define RNK 32        // dt_rank
#define ML (BB*LL)    // 2048 rows

__device__ __forceinline__ float sigmoidf_(float v) { return 1.f / (1.f + __expf(-v)); }
__device__ __forceinline__ float siluf_(float v) { return v * sigmoidf_(v); }

// ---------------- GEMM: C[M,N] = A[M,K] @ W[N,K]^T, EPI: 0 none, 1 +bias, 2 +bias+gelu ----------------
template<int EPI>
__global__ __launch_bounds__(256) void gemm_nt(const float* __restrict__ A,
                                               const float* __restrict__ W,
                                               const float* __restrict__ bias,
                                               float* __restrict__ C,
                                               int M, int N, int Kd)
{
  __shared__ float As[16][68];   // [k][m], pitch 68 keeps float4 alignment
  __shared__ float Bs[16][68];   // [k][n]
  const int bm = blockIdx.y * 64, bn = blockIdx.x * 64;
  const int tid = threadIdx.x;
  const int tx = tid & 15, ty = tid >> 4;       // 16x16 thread grid, 4x4 outputs each
  const int lr = tid >> 2, lc = (tid & 3) * 4;  // loader coords: row 0..63, col {0,4,8,12}
  float acc[4][4] = {};
  for (int k0 = 0; k0 < Kd; k0 += 16) {
    float4 av = *(const float4*)&A[(size_t)(bm + lr) * Kd + k0 + lc];
    float4 wv = *(const float4*)&W[(size_t)(bn + lr) * Kd + k0 + lc];
    As[lc + 0][lr] = av.x; As[lc + 1][lr] = av.y; As[lc + 2][lr] = av.z; As[lc + 3][lr] = av.w;
    Bs[lc + 0][lr] = wv.x; Bs[lc + 1][lr] = wv.y; Bs[lc + 2][lr] = wv.z; Bs[lc + 3][lr] = wv.w;
    __syncthreads();
#pragma unroll
    for (int k = 0; k < 16; ++k) {
      float a0 = As[k][ty * 4 + 0], a1 = As[k][ty * 4 + 1], a2 = As[k][ty * 4 + 2], a3 = As[k][ty * 4 + 3];
      float b0 = Bs[k][tx * 4 + 0], b1 = Bs[k][tx * 4 + 1], b2 = Bs[k][tx * 4 + 2], b3 = Bs[k][tx * 4 + 3];
      acc[0][0] = fmaf(a0, b0, acc[0][0]); acc[0][1] = fmaf(a0, b1, acc[0][1]);
      acc[0][2] = fmaf(a0, b2, acc[0][2]); acc[0][3] = fmaf(a0, b3, acc[0][3]);
      acc[1][0] = fmaf(a1, b0, acc[1][0]); acc[1][1] = fmaf(a1, b1, acc[1][1]);
      acc[1][2] = fmaf(a1, b2, acc[1][2]); acc[1][3] = fmaf(a1, b3, acc[1][3]);
      acc[2][0] = fmaf(a2, b0, acc[2][0]); acc[2][1] = fmaf(a2, b1, acc[2][1]);
      acc[2][2] = fmaf(a2, b2, acc[2][2]); acc[2][3] = fmaf(a2, b3, acc[2][3]);
      acc[3][0] = fmaf(a3, b0, acc[3][0]); acc[3][1] = fmaf(a3, b1, acc[3][1]);
      acc[3][2] = fmaf(a3, b2, acc[3][2]); acc[3][3] = fmaf(a3, b3, acc[3][3]);
    }
    __syncthreads();
  }
#pragma unroll
  for (int i = 0; i < 4; ++i) {
    int row = bm + ty * 4 + i;
    int col = bn + tx * 4;
    float4 v;
    float* pv = &v.x;
#pragma unroll
    for (int j = 0; j < 4; ++j) {
      float t = acc[i][j];
      if (EPI >= 1) t += bias[col + j];
      if (EPI == 2) t = 0.5f * t * (1.f + erff(t * 0.70710678118654752f));
      pv[j] = t;
    }
    *(float4*)&C[(size_t)row * N + col] = v;
  }
}

// ---------------- depthwise causal conv (K=4) + SiLU.  u lives in xz[:, 0:DIN] (row stride 2*DIN) ----------------
__global__ __launch_bounds__(256) void conv_silu(const float* __restrict__ xz,
                                                 const float* __restrict__ conv_w,
                                                 const float* __restrict__ conv_b,
                                                 float* __restrict__ uc)
{
  int idx = blockIdx.x * 256 + threadIdx.x;           // over B*L*DIN
  int d = idx & (DIN - 1);
  int bl = idx >> 10;                                  // b*L + l
  int l = bl & (LL - 1);
  int b = bl >> 10;
  float acc = conv_b[d];
#pragma unroll
  for (int k = 0; k < 4; ++k) {
    int ls = l - 3 + k;
    float uv = (ls >= 0) ? xz[((size_t)(b * LL + ls)) * (2 * DIN) + d] : 0.f;
    acc = fmaf(uv, conv_w[d * 4 + k], acc);
  }
  uc[idx] = siluf_(acc);
}

// ---------------- x_proj: xdbl[m, 0:64] = uc[m,:] @ W_xproj[64, DIN]^T ----------------
__global__ __launch_bounds__(64) void xproj_kernel(const float* __restrict__ uc,
                                                   const float* __restrict__ Wx,
                                                   float* __restrict__ xdbl)
{
  int m = blockIdx.x;
  int j = threadIdx.x;  // 0..63
  const float* a = &uc[(size_t)m * DIN];
  const float* w = &Wx[(size_t)j * DIN];
  float acc = 0.f;
  for (int k = 0; k < DIN; k += 4) {
    float4 av = *(const float4*)&a[k];
    float4 wv = *(const float4*)&w[k];
    acc = fmaf(av.x, wv.x, acc);
    acc = fmaf(av.y, wv.y, acc);
    acc = fmaf(av.z, wv.z, acc);
    acc = fmaf(av.w, wv.w, acc);
  }
  xdbl[m * 64 + j] = acc;
}

// ---------------- dt = softplus(dt_r @ W_dt^T + b_dt) ----------------
__global__ __launch_bounds__(256) void dtproj_kernel(const float* __restrict__ xdbl,
                                                     const float* __restrict__ Wdt,
                                                     const float* __restrict__ bdt,
                                                     float* __restrict__ dt)
{
  int idx = blockIdx.x * 256 + threadIdx.x;  // over ML*DIN
  int d = idx & (DIN - 1);
  int m = idx >> 10;
  const float4* xr = (const float4*)&xdbl[m * 64];       // first 32 = dt_r
  const float4* wr = (const float4*)&Wdt[(size_t)d * RNK];
  float acc = bdt[d];
#pragma unroll
  for (int q = 0; q < 8; ++q) {
    float4 xv = xr[q], wv = wr[q];
    acc = fmaf(xv.x, wv.x, acc);
    acc = fmaf(xv.y, wv.y, acc);
    acc = fmaf(xv.z, wv.z, acc);
    acc = fmaf(xv.w, wv.w, acc);
  }
  // stable softplus
  float sp = fmaxf(acc, 0.f) + log1pf(__expf(-fabsf(acc)));
  dt[idx] = sp;
}

// ---------------- selective scan, fused +u*D_skip and *silu(z) gating ----------------
// thread = (b, d, n): lane n = tid&15; 4 d's per 64-thread block
__global__ __launch_bounds__(64) void scan_kernel(const float* __restrict__ dt,
                                                  const float* __restrict__ uc,
                                                  const float* __restrict__ xz,
                                                  const float* __restrict__ xdbl,
                                                  const float* __restrict__ A_log,
                                                  const float* __restrict__ D_skip,
                                                  float* __restrict__ yg)
{
  int n = threadIdx.x & 15;
  int g = threadIdx.x >> 4;            // 0..3
  int chunk = blockIdx.x;              // 0..511
  int b = chunk >> 8;
  int d = (chunk & 255) * 4 + g;
  float Ad = -__expf(A_log[d * NS + n]);
  float Dd = D_skip[d];
  float h = 0.f;
  const float* dtp = dt + (size_t)b * LL * DIN + d;
  const float* ucp = uc + (size_t)b * LL * DIN + d;
  const float* zp  = xz + (size_t)b * LL * (2 * DIN) + DIN + d;
  const float* xd  = xdbl + (size_t)b * LL * 64;
  float* outp = yg + (size_t)b * LL * DIN + d;
  for (int t = 0; t < LL; ++t) {
    float dtv = dtp[(size_t)t * DIN];
    float ucv = ucp[(size_t)t * DIN];
    float Bv = xd[t * 64 + 32 + n];
    float Cv = xd[t * 64 + 48 + n];
    float dA = __expf(dtv * Ad);
    h = fmaf(dA, h, dtv * Bv * ucv);
    float p = h * Cv;
    p += __shfl_xor(p, 1, 16);
    p += __shfl_xor(p, 2, 16);
    p += __shfl_xor(p, 4, 16);
    p += __shfl_xor(p, 8, 16);
    if (n == 0) {
      float y = fmaf(ucv, Dd, p);
      float zv = zp[(size_t)t * (2 * DIN)];
      outp[(size_t)t * DIN] = y * siluf_(zv);
    }
  }
}

// ---------------- LN1: r = layernorm(x - m) * g1 + b1 ----------------
__global__ __launch_bounds__(256) void ln1_kernel(const float* __restrict__ x,
                                                  const float* __restrict__ m,
                                                  const float* __restrict__ g,
                                                  const float* __restrict__ b,
                                                  float* __restrict__ r)
{
  int row = blockIdx.x;
  int tid = threadIdx.x;
  size_t base = (size_t)row * DD;
  float2 xv = *(const float2*)&x[base + tid * 2];
  float2 mv = *(const float2*)&m[base + tid * 2];
  float v0 = xv.x - mv.x, v1 = xv.y - mv.y;
  float s = v0 + v1, ss = v0 * v0 + v1 * v1;
#pragma unroll
  for (int off = 32; off; off >>= 1) { s += __shfl_down(s, off, 64); ss += __shfl_down(ss, off, 64); }
  __shared__ float sm[8];
  int w = tid >> 6;
  if ((tid & 63) == 0) { sm[w] = s; sm[4 + w] = ss; }
  __syncthreads();
  float S = sm[0] + sm[1] + sm[2] + sm[3];
  float SS = sm[4] + sm[5] + sm[6] + sm[7];
  float mean = S * (1.f / DD);
  float var = SS * (1.f / DD) - mean * mean;
  float rstd = rsqrtf(var + 1e-5f);
  float2 gv = *(const float2*)&g[tid * 2];
  float2 bv = *(const float2*)&b[tid * 2];
  float2 o;
  o.x = (v0 - mean) * rstd * gv.x + bv.x;
  o.y = (v1 - mean) * rstd * gv.y + bv.y;
  *(float2*)&r[base + tid * 2] = o;
}

// ---------------- final: out = layernorm(silu(r - ff)) * g2 + b2 + x ----------------
__global__ __launch_bounds__(256) void final_kernel(const float* __restrict__ r,
                                                    const float* __restrict__ ff,
                                                    const float* __restrict__ x,
                                                    const float* __restrict__ g,
                                                    const float* __restrict__ b,
                                                    float* __restrict__ out)
{
  int row = blockIdx.x;
  int tid = threadIdx.x;
  size_t base = (size_t)row * DD;
  float2 rv = *(const float2*)&r[base + tid * 2];
  float2 fv = *(const float2*)&ff[base + tid * 2];
  float v0 = rv.x - fv.x, v1 = rv.y - fv.y;
  v0 = siluf_(v0); v1 = siluf_(v1);
  float s = v0 + v1, ss = v0 * v0 + v1 * v1;
#pragma unroll
  for (int off = 32; off; off >>= 1) { s += __shfl_down(s, off, 64); ss += __shfl_down(ss, off, 64); }
  __shared__ float sm[8];
  int w = tid >> 6;
  if ((tid & 63) == 0) { sm[w] = s; sm[4 + w] = ss; }
  __syncthreads();
  float S = sm[0] + sm[1] + sm[2] + sm[3];
  float SS = sm[4] + sm[5] + sm[6] + sm[7];
  float mean = S * (1.f / DD);
  float var = SS * (1.f / DD) - mean * mean;
  float rstd = rsqrtf(var + 1e-5f);
  float2 gv = *(const float2*)&g[tid * 2];
  float2 bv = *(const float2*)&b[tid * 2];
  float2 xv = *(const float2*)&x[base + tid * 2];
  float2 o;
  o.x = (v0 - mean) * rstd * gv.x + bv.x + xv.x;
  o.y = (v1 - mean) * rstd * gv.y + bv.y + xv.y;
  *(float2*)&out[base + tid * 2] = o;
}

extern "C" void kernel_launch(void* const* d_in, const int* in_sizes, int n_in,
                              void* d_out, int out_size, void* d_ws, size_t ws_size,
                              hipStream_t stream)
{
  const float* x      = (const float*)d_in[0];
  const float* W_in   = (const float*)d_in[1];
  const float* conv_w = (const float*)d_in[2];
  const float* conv_b = (const float*)d_in[3];
  const float* W_xp   = (const float*)d_in[4];
  const float* W_dt   = (const float*)d_in[5];
  const float* b_dt   = (const float*)d_in[6];
  const float* A_log  = (const float*)d_in[7];
  const float* D_skip = (const float*)d_in[8];
  const float* W_out  = (const float*)d_in[9];
  const float* g1     = (const float*)d_in[10];
  const float* b1     = (const float*)d_in[11];
  const float* W_ff1  = (const float*)d_in[12];
  const float* b_ff1  = (const float*)d_in[13];
  const float* W_ff2  = (const float*)d_in[14];
  const float* b_ff2  = (const float*)d_in[15];
  const float* g2     = (const float*)d_in[16];
  const float* b2     = (const float*)d_in[17];
  float* out = (float*)d_out;

  float* ws = (float*)d_ws;
  float* xz   = ws;                    // 4194304  (ML x 2048)
  float* uc   = xz + 4194304;          // 2097152  (ML x 1024)
  float* xdbl = uc + 2097152;          // 131072   (ML x 64)
  float* dtb  = xdbl + 131072;         // 2097152  (ML x 1024)
  float* yg   = dtb + 2097152;         // 2097152  (ML x 1024)
  float* mb   = yg + 2097152;          // 1048576  (ML x 512)  m, later ff
  float* rb   = mb + 1048576;          // 1048576  (ML x 512)
  float* ffh  = rb + 1048576;          // 2097152  (ML x 1024)

  // 1. in_proj: xz[2048,2048] = x[2048,512] @ W_in^T
  gemm_nt<0><<<dim3(2048 / 64, ML / 64), 256, 0, stream>>>(x, W_in, nullptr, xz, ML, 2048, DD);
  // 2. conv + silu -> uc
  conv_silu<<<(ML * DIN) / 256, 256, 0, stream>>>(xz, conv_w, conv_b, uc);
  // 3. x_proj -> xdbl[2048,64]
  xproj_kernel<<<ML, 64, 0, stream>>>(uc, W_xp, xdbl);
  // 4. dt_proj + softplus -> dtb[2048,1024]
  dtproj_kernel<<<(ML * DIN) / 256, 256, 0, stream>>>(xdbl, W_dt, b_dt, dtb);
  // 5. scan (+D_skip, *silu(z)) -> yg[2048,1024]
  scan_kernel<<<BB * (DIN / 4), 64, 0, stream>>>(dtb, uc, xz, xdbl, A_log, D_skip, yg);
  // 6. out_proj: mb[2048,512] = yg @ W_out^T
  gemm_nt<0><<<dim3(DD / 64, ML / 64), 256, 0, stream>>>(yg, W_out, nullptr, mb, ML, DD, DIN);
  // 7. LN1(x - m) -> rb
  ln1_kernel<<<ML, 256, 0, stream>>>(x, mb, g1, b1, rb);
  // 8. ff1 + bias + gelu -> ffh[2048,1024]
  gemm_nt<2><<<dim3(DIN / 64, ML / 64), 256, 0, stream>>>(rb, W_ff1, b_ff1, ffh, ML, DIN, DD);
  // 9. ff2 + bias -> mb (reuse as ff)
  gemm_nt<1><<<dim3(DD / 64, ML / 64), 256, 0, stream>>>(ffh, W_ff2, b_ff2, mb, ML, DD, DIN);
  // 10. final LN2(silu(r - ff)) + x -> out
  final_kernel<<<ML, 256, 0, stream>>>(rb, mb, x, g2, b2, out);
}

// Round 2
// 376.070 us; speedup vs baseline: 2.7148x; 2.7148x over previous
//
#include <hip/hip_runtime.h>
#include <math.h>

#define BB 2
#define LL 1024
#define DD 512
#define DIN 1024      // d_inner
#define NS 16         // d_state
#define RNK 32        // dt_rank
#define ML (BB*LL)    // 2048 rows
#define CT 64         // scan chunk length
#define NC (LL/CT)    // 16 chunks

__device__ __forceinline__ float sigmoidf_(float v) { return 1.f / (1.f + __expf(-v)); }
__device__ __forceinline__ float siluf_(float v) { return v * sigmoidf_(v); }

// ---------------- GEMM: C[M,N] = A[M,K] @ W[N,K]^T, EPI: 0 none, 1 +bias, 2 +bias+gelu ----------------
template<int EPI>
__global__ __launch_bounds__(256) void gemm_nt(const float* __restrict__ A,
                                               const float* __restrict__ W,
                                               const float* __restrict__ bias,
                                               float* __restrict__ C,
                                               int M, int N, int Kd)
{
  __shared__ float As[16][68];
  __shared__ float Bs[16][68];
  const int bm = blockIdx.y * 64, bn = blockIdx.x * 64;
  const int tid = threadIdx.x;
  const int tx = tid & 15, ty = tid >> 4;
  const int lr = tid >> 2, lc = (tid & 3) * 4;
  float acc[4][4] = {};
  for (int k0 = 0; k0 < Kd; k0 += 16) {
    float4 av = *(const float4*)&A[(size_t)(bm + lr) * Kd + k0 + lc];
    float4 wv = *(const float4*)&W[(size_t)(bn + lr) * Kd + k0 + lc];
    As[lc + 0][lr] = av.x; As[lc + 1][lr] = av.y; As[lc + 2][lr] = av.z; As[lc + 3][lr] = av.w;
    Bs[lc + 0][lr] = wv.x; Bs[lc + 1][lr] = wv.y; Bs[lc + 2][lr] = wv.z; Bs[lc + 3][lr] = wv.w;
    __syncthreads();
#pragma unroll
    for (int k = 0; k < 16; ++k) {
      float a0 = As[k][ty * 4 + 0], a1 = As[k][ty * 4 + 1], a2 = As[k][ty * 4 + 2], a3 = As[k][ty * 4 + 3];
      float b0 = Bs[k][tx * 4 + 0], b1 = Bs[k][tx * 4 + 1], b2 = Bs[k][tx * 4 + 2], b3 = Bs[k][tx * 4 + 3];
      acc[0][0] = fmaf(a0, b0, acc[0][0]); acc[0][1] = fmaf(a0, b1, acc[0][1]);
      acc[0][2] = fmaf(a0, b2, acc[0][2]); acc[0][3] = fmaf(a0, b3, acc[0][3]);
      acc[1][0] = fmaf(a1, b0, acc[1][0]); acc[1][1] = fmaf(a1, b1, acc[1][1]);
      acc[1][2] = fmaf(a1, b2, acc[1][2]); acc[1][3] = fmaf(a1, b3, acc[1][3]);
      acc[2][0] = fmaf(a2, b0, acc[2][0]); acc[2][1] = fmaf(a2, b1, acc[2][1]);
      acc[2][2] = fmaf(a2, b2, acc[2][2]); acc[2][3] = fmaf(a2, b3, acc[2][3]);
      acc[3][0] = fmaf(a3, b0, acc[3][0]); acc[3][1] = fmaf(a3, b1, acc[3][1]);
      acc[3][2] = fmaf(a3, b2, acc[3][2]); acc[3][3] = fmaf(a3, b3, acc[3][3]);
    }
    __syncthreads();
  }
#pragma unroll
  for (int i = 0; i < 4; ++i) {
    int row = bm + ty * 4 + i;
    int col = bn + tx * 4;
    float4 v;
    float* pv = &v.x;
#pragma unroll
    for (int j = 0; j < 4; ++j) {
      float t = acc[i][j];
      if (EPI >= 1) t += bias[col + j];
      if (EPI == 2) t = 0.5f * t * (1.f + erff(t * 0.70710678118654752f));
      pv[j] = t;
    }
    *(float4*)&C[(size_t)row * N + col] = v;
  }
}

// ---------------- depthwise causal conv (K=4) + SiLU ----------------
__global__ __launch_bounds__(256) void conv_silu(const float* __restrict__ xz,
                                                 const float* __restrict__ conv_w,
                                                 const float* __restrict__ conv_b,
                                                 float* __restrict__ uc)
{
  int idx = blockIdx.x * 256 + threadIdx.x;
  int d = idx & (DIN - 1);
  int bl = idx >> 10;
  int l = bl & (LL - 1);
  int b = bl >> 10;
  float acc = conv_b[d];
#pragma unroll
  for (int k = 0; k < 4; ++k) {
    int ls = l - 3 + k;
    float uv = (ls >= 0) ? xz[((size_t)(b * LL + ls)) * (2 * DIN) + d] : 0.f;
    acc = fmaf(uv, conv_w[d * 4 + k], acc);
  }
  uc[idx] = siluf_(acc);
}

// ---------------- x_proj ----------------
__global__ __launch_bounds__(64) void xproj_kernel(const float* __restrict__ uc,
                                                   const float* __restrict__ Wx,
                                                   float* __restrict__ xdbl)
{
  int m = blockIdx.x;
  int j = threadIdx.x;
  const float* a = &uc[(size_t)m * DIN];
  const float* w = &Wx[(size_t)j * DIN];
  float acc = 0.f;
  for (int k = 0; k < DIN; k += 4) {
    float4 av = *(const float4*)&a[k];
    float4 wv = *(const float4*)&w[k];
    acc = fmaf(av.x, wv.x, acc);
    acc = fmaf(av.y, wv.y, acc);
    acc = fmaf(av.z, wv.z, acc);
    acc = fmaf(av.w, wv.w, acc);
  }
  xdbl[m * 64 + j] = acc;
}

// ---------------- dt = softplus(dt_r @ W_dt^T + b_dt) ----------------
__global__ __launch_bounds__(256) void dtproj_kernel(const float* __restrict__ xdbl,
                                                     const float* __restrict__ Wdt,
                                                     const float* __restrict__ bdt,
                                                     float* __restrict__ dt)
{
  int idx = blockIdx.x * 256 + threadIdx.x;
  int d = idx & (DIN - 1);
  int m = idx >> 10;
  const float4* xr = (const float4*)&xdbl[m * 64];
  const float4* wr = (const float4*)&Wdt[(size_t)d * RNK];
  float acc = bdt[d];
#pragma unroll
  for (int q = 0; q < 8; ++q) {
    float4 xv = xr[q], wv = wr[q];
    acc = fmaf(xv.x, wv.x, acc);
    acc = fmaf(xv.y, wv.y, acc);
    acc = fmaf(xv.z, wv.z, acc);
    acc = fmaf(xv.w, wv.w, acc);
  }
  float sp = fmaxf(acc, 0.f) + log1pf(__expf(-fabsf(acc)));
  dt[idx] = sp;
}

// ================= chunked selective scan =================
// state layout: [chunk][b*DIN+d][n]  (coalesced for phase1 writes / phase3 reads)

// phase 1: per-chunk local scan (h0=0) + decay product.
// block 256 = 16 d x 16 n; grid (NC, DIN/16, B)
__global__ __launch_bounds__(256) void scan_phase1(const float* __restrict__ dt,
                                                   const float* __restrict__ uc,
                                                   const float* __restrict__ xdbl,
                                                   const float* __restrict__ A_log,
                                                   float* __restrict__ aprodG,
                                                   float* __restrict__ hlocG)
{
  __shared__ float dts[CT][16];
  __shared__ float us[CT][16];
  __shared__ float Bls[CT][16];
  const int c = blockIdx.x, dblk = blockIdx.y, b = blockIdx.z;
  const int tid = threadIdx.x;
  const int n = tid & 15, dg = tid >> 4;
  const int d0 = dblk * 16, t0 = c * CT;
  for (int i = tid; i < CT * 16; i += 256) {
    int r = i >> 4, col = i & 15;
    size_t row = (size_t)(b * LL + t0 + r);
    size_t g = row * DIN + d0 + col;
    dts[r][col] = dt[g];
    us[r][col]  = uc[g];
    Bls[r][col] = xdbl[row * 64 + 32 + col];
  }
  __syncthreads();
  const int d = d0 + dg;
  const float Ad = -__expf(A_log[d * NS + n]);
  float h = 0.f, ap = 1.f;
#pragma unroll 8
  for (int t = 0; t < CT; ++t) {
    float dtv = dts[t][dg];
    float a = __expf(dtv * Ad);
    h = fmaf(a, h, dtv * Bls[t][n] * us[t][dg]);
    ap *= a;
  }
  size_t o = (size_t)c * (BB * DIN * NS) + (size_t)(b * DIN + d) * NS + n;
  aprodG[o] = ap;
  hlocG[o] = h;
}

// phase 2: sequential combine over 16 chunks per (b,d,n) -> chunk-entry states
__global__ __launch_bounds__(256) void scan_phase2(const float* __restrict__ aprodG,
                                                   const float* __restrict__ hlocG,
                                                   float* __restrict__ hinitG)
{
  const int idx = blockIdx.x * 256 + threadIdx.x;   // (b*DIN+d)*NS+n, 32768 total
  const int STRIDE = BB * DIN * NS;
  float ap[NC], hl[NC];
#pragma unroll
  for (int c = 0; c < NC; ++c) {
    ap[c] = aprodG[c * STRIDE + idx];
    hl[c] = hlocG[c * STRIDE + idx];
  }
  float H = 0.f;
#pragma unroll
  for (int c = 0; c < NC; ++c) {
    hinitG[c * STRIDE + idx] = H;
    H = fmaf(ap[c], H, hl[c]);
  }
}

// phase 3: replay chunk from hinit, reduce over n, fuse D_skip + silu(z) gate
// block 256 = 16 d x 16 n; grid (NC, DIN/16, B)
__global__ __launch_bounds__(256) void scan_phase3(const float* __restrict__ dt,
                                                   const float* __restrict__ uc,
                                                   const float* __restrict__ xz,
                                                   const float* __restrict__ xdbl,
                                                   const float* __restrict__ A_log,
                                                   const float* __restrict__ D_skip,
                                                   const float* __restrict__ hinitG,
                                                   float* __restrict__ yg)
{
  __shared__ float dts[CT][16];
  __shared__ float us[CT][16];
  __shared__ float Bls[CT][16];
  __shared__ float Cls[CT][16];
  __shared__ float zs[CT][16];
  __shared__ float ys[CT][16];
  const int c = blockIdx.x, dblk = blockIdx.y, b = blockIdx.z;
  const int tid = threadIdx.x;
  const int n = tid & 15, dg = tid >> 4;
  const int d0 = dblk * 16, t0 = c * CT;
  for (int i = tid; i < CT * 16; i += 256) {
    int r = i >> 4, col = i & 15;
    size_t row = (size_t)(b * LL + t0 + r);
    size_t g = row * DIN + d0 + col;
    dts[r][col] = dt[g];
    us[r][col]  = uc[g];
    Bls[r][col] = xdbl[row * 64 + 32 + col];
    Cls[r][col] = xdbl[row * 64 + 48 + col];
    zs[r][col]  = xz[row * (2 * DIN) + DIN + d0 + col];
  }
  __syncthreads();
  const int d = d0 + dg;
  const float Ad = -__expf(A_log[d * NS + n]);
  const float Dd = D_skip[d];
  float h = hinitG[(size_t)c * (BB * DIN * NS) + (size_t)(b * DIN + d) * NS + n];
#pragma unroll 4
  for (int t = 0; t < CT; ++t) {
    float dtv = dts[t][dg];
    float ucv = us[t][dg];
    float a = __expf(dtv * Ad);
    h = fmaf(a, h, dtv * Bls[t][n] * ucv);
    float p = h * Cls[t][n];
    p += __shfl_xor(p, 1, 16);
    p += __shfl_xor(p, 2, 16);
    p += __shfl_xor(p, 4, 16);
    p += __shfl_xor(p, 8, 16);
    if (n == 0) {
      ys[t][dg] = fmaf(ucv, Dd, p) * siluf_(zs[t][dg]);
    }
  }
  __syncthreads();
  for (int i = tid; i < CT * 16; i += 256) {
    int r = i >> 4, col = i & 15;
    yg[((size_t)(b * LL + t0 + r)) * DIN + d0 + col] = ys[r][col];
  }
}

// ---------------- LN1: r = layernorm(x - m) * g1 + b1 ----------------
__global__ __launch_bounds__(256) void ln1_kernel(const float* __restrict__ x,
                                                  const float* __restrict__ m,
                                                  const float* __restrict__ g,
                                                  const float* __restrict__ b,
                                                  float* __restrict__ r)
{
  int row = blockIdx.x;
  int tid = threadIdx.x;
  size_t base = (size_t)row * DD;
  float2 xv = *(const float2*)&x[base + tid * 2];
  float2 mv = *(const float2*)&m[base + tid * 2];
  float v0 = xv.x - mv.x, v1 = xv.y - mv.y;
  float s = v0 + v1, ss = v0 * v0 + v1 * v1;
#pragma unroll
  for (int off = 32; off; off >>= 1) { s += __shfl_down(s, off, 64); ss += __shfl_down(ss, off, 64); }
  __shared__ float sm[8];
  int w = tid >> 6;
  if ((tid & 63) == 0) { sm[w] = s; sm[4 + w] = ss; }
  __syncthreads();
  float S = sm[0] + sm[1] + sm[2] + sm[3];
  float SS = sm[4] + sm[5] + sm[6] + sm[7];
  float mean = S * (1.f / DD);
  float var = SS * (1.f / DD) - mean * mean;
  float rstd = rsqrtf(var + 1e-5f);
  float2 gv = *(const float2*)&g[tid * 2];
  float2 bv = *(const float2*)&b[tid * 2];
  float2 o;
  o.x = (v0 - mean) * rstd * gv.x + bv.x;
  o.y = (v1 - mean) * rstd * gv.y + bv.y;
  *(float2*)&r[base + tid * 2] = o;
}

// ---------------- final: out = layernorm(silu(r - ff)) * g2 + b2 + x ----------------
__global__ __launch_bounds__(256) void final_kernel(const float* __restrict__ r,
                                                    const float* __restrict__ ff,
                                                    const float* __restrict__ x,
                                                    const float* __restrict__ g,
                                                    const float* __restrict__ b,
                                                    float* __restrict__ out)
{
  int row = blockIdx.x;
  int tid = threadIdx.x;
  size_t base = (size_t)row * DD;
  float2 rv = *(const float2*)&r[base + tid * 2];
  float2 fv = *(const float2*)&ff[base + tid * 2];
  float v0 = rv.x - fv.x, v1 = rv.y - fv.y;
  v0 = siluf_(v0); v1 = siluf_(v1);
  float s = v0 + v1, ss = v0 * v0 + v1 * v1;
#pragma unroll
  for (int off = 32; off; off >>= 1) { s += __shfl_down(s, off, 64); ss += __shfl_down(ss, off, 64); }
  __shared__ float sm[8];
  int w = tid >> 6;
  if ((tid & 63) == 0) { sm[w] = s; sm[4 + w] = ss; }
  __syncthreads();
  float S = sm[0] + sm[1] + sm[2] + sm[3];
  float SS = sm[4] + sm[5] + sm[6] + sm[7];
  float mean = S * (1.f / DD);
  float var = SS * (1.f / DD) - mean * mean;
  float rstd = rsqrtf(var + 1e-5f);
  float2 gv = *(const float2*)&g[tid * 2];
  float2 bv = *(const float2*)&b[tid * 2];
  float2 xv = *(const float2*)&x[base + tid * 2];
  float2 o;
  o.x = (v0 - mean) * rstd * gv.x + bv.x + xv.x;
  o.y = (v1 - mean) * rstd * gv.y + bv.y + xv.y;
  *(float2*)&out[base + tid * 2] = o;
}

extern "C" void kernel_launch(void* const* d_in, const int* in_sizes, int n_in,
                              void* d_out, int out_size, void* d_ws, size_t ws_size,
                              hipStream_t stream)
{
  const float* x      = (const float*)d_in[0];
  const float* W_in   = (const float*)d_in[1];
  const float* conv_w = (const float*)d_in[2];
  const float* conv_b = (const float*)d_in[3];
  const float* W_xp   = (const float*)d_in[4];
  const float* W_dt   = (const float*)d_in[5];
  const float* b_dt   = (const float*)d_in[6];
  const float* A_log  = (const float*)d_in[7];
  const float* D_skip = (const float*)d_in[8];
  const float* W_out  = (const float*)d_in[9];
  const float* g1     = (const float*)d_in[10];
  const float* b1     = (const float*)d_in[11];
  const float* W_ff1  = (const float*)d_in[12];
  const float* b_ff1  = (const float*)d_in[13];
  const float* W_ff2  = (const float*)d_in[14];
  const float* b_ff2  = (const float*)d_in[15];
  const float* g2     = (const float*)d_in[16];
  const float* b2     = (const float*)d_in[17];
  float* out = (float*)d_out;

  float* ws = (float*)d_ws;
  float* xz   = ws;                    // ML x 2048
  float* uc   = xz + 4194304;          // ML x 1024
  float* xdbl = uc + 2097152;          // ML x 64
  float* dtb  = xdbl + 131072;         // ML x 1024
  float* yg   = dtb + 2097152;         // ML x 1024
  float* mb   = yg + 2097152;          // ML x 512 (m, later ff)
  float* rb   = mb + 1048576;          // ML x 512
  float* ffh  = rb + 1048576;          // ML x 1024 (ff1 out; scan states overlap here first)
  // scan chunk states (dead before ff1 runs) overlap the ffh region:
  float* aprodG = ffh;                 // NC*BB*DIN*NS = 524288
  float* hlocG  = ffh + 524288;
  float* hinitG = ffh + 1048576;

  // 1. in_proj
  gemm_nt<0><<<dim3(2048 / 64, ML / 64), 256, 0, stream>>>(x, W_in, nullptr, xz, ML, 2048, DD);
  // 2. conv + silu
  conv_silu<<<(ML * DIN) / 256, 256, 0, stream>>>(xz, conv_w, conv_b, uc);
  // 3. x_proj
  xproj_kernel<<<ML, 64, 0, stream>>>(uc, W_xp, xdbl);
  // 4. dt_proj + softplus
  dtproj_kernel<<<(ML * DIN) / 256, 256, 0, stream>>>(xdbl, W_dt, b_dt, dtb);
  // 5. chunked scan
  scan_phase1<<<dim3(NC, DIN / 16, BB), 256, 0, stream>>>(dtb, uc, xdbl, A_log, aprodG, hlocG);
  scan_phase2<<<(BB * DIN * NS) / 256, 256, 0, stream>>>(aprodG, hlocG, hinitG);
  scan_phase3<<<dim3(NC, DIN / 16, BB), 256, 0, stream>>>(dtb, uc, xz, xdbl, A_log, D_skip,
                                                          hinitG, yg);
  // 6. out_proj
  gemm_nt<0><<<dim3(DD / 64, ML / 64), 256, 0, stream>>>(yg, W_out, nullptr, mb, ML, DD, DIN);
  // 7. LN1(x - m)
  ln1_kernel<<<ML, 256, 0, stream>>>(x, mb, g1, b1, rb);
  // 8. ff1 + bias + gelu
  gemm_nt<2><<<dim3(DIN / 64, ML / 64), 256, 0, stream>>>(rb, W_ff1, b_ff1, ffh, ML, DIN, DD);
  // 9. ff2 + bias
  gemm_nt<1><<<dim3(DD / 64, ML / 64), 256, 0, stream>>>(ffh, W_ff2, b_ff2, mb, ML, DD, DIN);
  // 10. final
  final_kernel<<<ML, 256, 0, stream>>>(rb, mb, x, g2, b2, out);
}

// Round 3
// 276.393 us; speedup vs baseline: 3.6938x; 1.3606x over previous
//
#include <hip/hip_runtime.h>
#include <math.h>

#define BB 2
#define LL 1024
#define DD 512
#define DIN 1024      // d_inner
#define NS 16         // d_state
#define RNK 32        // dt_rank
#define ML (BB*LL)    // 2048 rows
#define CT 64         // scan chunk length
#define NC (LL/CT)    // 16 chunks

typedef unsigned short u16;
typedef unsigned int u32;

__device__ __forceinline__ float sigmoidf_(float v) { return 1.f / (1.f + __expf(-v)); }
__device__ __forceinline__ float siluf_(float v) { return v * sigmoidf_(v); }
__device__ __forceinline__ u16 f2bf(float f) {
  union { float f; u32 u; } c; c.f = f;
  u32 r = c.u + 0x7fffu + ((c.u >> 16) & 1u);
  return (u16)(r >> 16);
}

// ---------------- fp32 -> bf16 cast (n multiple of 2048) ----------------
__global__ __launch_bounds__(256) void cvt_bf16(const float* __restrict__ in,
                                                u16* __restrict__ out, int n)
{
  int i = (blockIdx.x * 256 + threadIdx.x) * 8;
  if (i >= n) return;
  float4 v0 = *(const float4*)&in[i];
  float4 v1 = *(const float4*)&in[i + 4];
  union { u16 u[8]; uint4 v; } p;
  p.u[0] = f2bf(v0.x); p.u[1] = f2bf(v0.y); p.u[2] = f2bf(v0.z); p.u[3] = f2bf(v0.w);
  p.u[4] = f2bf(v1.x); p.u[5] = f2bf(v1.y); p.u[6] = f2bf(v1.z); p.u[7] = f2bf(v1.w);
  *(uint4*)&out[i] = p.v;
}

// ---------------- bf16 MFMA GEMM: C[M,N] = A[M,K] @ W[N,K]^T ----------------
// EPI: 0 none, 1 +bias, 2 +bias+gelu.  OT: float or u16 (bf16 out)
using bf16x8 = __attribute__((ext_vector_type(8))) short;
using f32x4  = __attribute__((ext_vector_type(4))) float;

template<int EPI, typename OT>
__global__ __launch_bounds__(256) void gemm_bf16(const u16* __restrict__ A,
                                                 const u16* __restrict__ W,
                                                 const float* __restrict__ bias,
                                                 OT* __restrict__ C,
                                                 int M, int N, int K)
{
  __shared__ u16 As[128][40];   // pad to 40 (80B row): ~2-way bank alias max
  __shared__ u16 Bs[128][40];
  const int bm = blockIdx.y * 128, bn = blockIdx.x * 128;
  const int tid = threadIdx.x;
  const int w = tid >> 6, l = tid & 63;
  const int wr = w >> 1, wc = w & 1;       // wave -> 64x64 quadrant
  const int lr = l & 15, lh = l >> 4;      // frag row, k-half
  const int sr0 = tid >> 2, sc0 = tid & 3; // staging: row, 16B-chunk col
  f32x4 acc[4][4] = {};
  for (int k0 = 0; k0 < K; k0 += 32) {
    uint4 a0 = *(const uint4*)&A[(size_t)(bm + sr0) * K + k0 + sc0 * 8];
    uint4 a1 = *(const uint4*)&A[(size_t)(bm + sr0 + 64) * K + k0 + sc0 * 8];
    uint4 b0 = *(const uint4*)&W[(size_t)(bn + sr0) * K + k0 + sc0 * 8];
    uint4 b1 = *(const uint4*)&W[(size_t)(bn + sr0 + 64) * K + k0 + sc0 * 8];
    __syncthreads();
    *(uint4*)&As[sr0][sc0 * 8] = a0;
    *(uint4*)&As[sr0 + 64][sc0 * 8] = a1;
    *(uint4*)&Bs[sr0][sc0 * 8] = b0;
    *(uint4*)&Bs[sr0 + 64][sc0 * 8] = b1;
    __syncthreads();
    bf16x8 af[4], bfr[4];
#pragma unroll
    for (int i = 0; i < 4; ++i) af[i]  = *(bf16x8*)&As[wr * 64 + i * 16 + lr][lh * 8];
#pragma unroll
    for (int j = 0; j < 4; ++j) bfr[j] = *(bf16x8*)&Bs[wc * 64 + j * 16 + lr][lh * 8];
#pragma unroll
    for (int i = 0; i < 4; ++i)
#pragma unroll
      for (int j = 0; j < 4; ++j)
        acc[i][j] = __builtin_amdgcn_mfma_f32_16x16x32_bf16(af[i], bfr[j], acc[i][j], 0, 0, 0);
  }
#pragma unroll
  for (int i = 0; i < 4; ++i) {
#pragma unroll
    for (int j = 0; j < 4; ++j) {
      int col = bn + wc * 64 + j * 16 + lr;
      float bv = (EPI >= 1) ? bias[col] : 0.f;
#pragma unroll
      for (int r = 0; r < 4; ++r) {
        int row = bm + wr * 64 + i * 16 + lh * 4 + r;
        float t = acc[i][j][r] + bv;
        if (EPI == 2) t = 0.5f * t * (1.f + erff(t * 0.70710678118654752f));
        if constexpr (sizeof(OT) == 2) C[(size_t)row * N + col] = (OT)f2bf(t);
        else                           C[(size_t)row * N + col] = (OT)t;
      }
    }
  }
}

// ---------------- depthwise causal conv (K=4) + SiLU ----------------
__global__ __launch_bounds__(256) void conv_silu(const float* __restrict__ xz,
                                                 const float* __restrict__ conv_w,
                                                 const float* __restrict__ conv_b,
                                                 float* __restrict__ uc)
{
  int idx = blockIdx.x * 256 + threadIdx.x;
  int d = idx & (DIN - 1);
  int bl = idx >> 10;
  int l = bl & (LL - 1);
  int b = bl >> 10;
  float acc = conv_b[d];
#pragma unroll
  for (int k = 0; k < 4; ++k) {
    int ls = l - 3 + k;
    float uv = (ls >= 0) ? xz[((size_t)(b * LL + ls)) * (2 * DIN) + d] : 0.f;
    acc = fmaf(uv, conv_w[d * 4 + k], acc);
  }
  uc[idx] = siluf_(acc);
}

// ---------------- x_proj ----------------
__global__ __launch_bounds__(64) void xproj_kernel(const float* __restrict__ uc,
                                                   const float* __restrict__ Wx,
                                                   float* __restrict__ xdbl)
{
  int m = blockIdx.x;
  int j = threadIdx.x;
  const float* a = &uc[(size_t)m * DIN];
  const float* w = &Wx[(size_t)j * DIN];
  float acc = 0.f;
  for (int k = 0; k < DIN; k += 4) {
    float4 av = *(const float4*)&a[k];
    float4 wv = *(const float4*)&w[k];
    acc = fmaf(av.x, wv.x, acc);
    acc = fmaf(av.y, wv.y, acc);
    acc = fmaf(av.z, wv.z, acc);
    acc = fmaf(av.w, wv.w, acc);
  }
  xdbl[m * 64 + j] = acc;
}

// ---------------- dt = softplus(dt_r @ W_dt^T + b_dt) ----------------
__global__ __launch_bounds__(256) void dtproj_kernel(const float* __restrict__ xdbl,
                                                     const float* __restrict__ Wdt,
                                                     const float* __restrict__ bdt,
                                                     float* __restrict__ dt)
{
  int idx = blockIdx.x * 256 + threadIdx.x;
  int d = idx & (DIN - 1);
  int m = idx >> 10;
  const float4* xr = (const float4*)&xdbl[m * 64];
  const float4* wr = (const float4*)&Wdt[(size_t)d * RNK];
  float acc = bdt[d];
#pragma unroll
  for (int q = 0; q < 8; ++q) {
    float4 xv = xr[q], wv = wr[q];
    acc = fmaf(xv.x, wv.x, acc);
    acc = fmaf(xv.y, wv.y, acc);
    acc = fmaf(xv.z, wv.z, acc);
    acc = fmaf(xv.w, wv.w, acc);
  }
  float sp = fmaxf(acc, 0.f) + log1pf(__expf(-fabsf(acc)));
  dt[idx] = sp;
}

// ================= chunked selective scan =================
__global__ __launch_bounds__(256) void scan_phase1(const float* __restrict__ dt,
                                                   const float* __restrict__ uc,
                                                   const float* __restrict__ xdbl,
                                                   const float* __restrict__ A_log,
                                                   float* __restrict__ aprodG,
                                                   float* __restrict__ hlocG)
{
  __shared__ float dts[CT][16];
  __shared__ float us[CT][16];
  __shared__ float Bls[CT][16];
  const int c = blockIdx.x, dblk = blockIdx.y, b = blockIdx.z;
  const int tid = threadIdx.x;
  const int n = tid & 15, dg = tid >> 4;
  const int d0 = dblk * 16, t0 = c * CT;
  for (int i = tid; i < CT * 16; i += 256) {
    int r = i >> 4, col = i & 15;
    size_t row = (size_t)(b * LL + t0 + r);
    size_t g = row * DIN + d0 + col;
    dts[r][col] = dt[g];
    us[r][col]  = uc[g];
    Bls[r][col] = xdbl[row * 64 + 32 + col];
  }
  __syncthreads();
  const int d = d0 + dg;
  const float Ad = -__expf(A_log[d * NS + n]);
  float h = 0.f, ap = 1.f;
#pragma unroll 8
  for (int t = 0; t < CT; ++t) {
    float dtv = dts[t][dg];
    float a = __expf(dtv * Ad);
    h = fmaf(a, h, dtv * Bls[t][n] * us[t][dg]);
    ap *= a;
  }
  size_t o = (size_t)c * (BB * DIN * NS) + (size_t)(b * DIN + d) * NS + n;
  aprodG[o] = ap;
  hlocG[o] = h;
}

__global__ __launch_bounds__(256) void scan_phase2(const float* __restrict__ aprodG,
                                                   const float* __restrict__ hlocG,
                                                   float* __restrict__ hinitG)
{
  const int idx = blockIdx.x * 256 + threadIdx.x;
  const int STRIDE = BB * DIN * NS;
  float ap[NC], hl[NC];
#pragma unroll
  for (int c = 0; c < NC; ++c) {
    ap[c] = aprodG[c * STRIDE + idx];
    hl[c] = hlocG[c * STRIDE + idx];
  }
  float H = 0.f;
#pragma unroll
  for (int c = 0; c < NC; ++c) {
    hinitG[c * STRIDE + idx] = H;
    H = fmaf(ap[c], H, hl[c]);
  }
}

// phase 3: replay chunk, reduce over n, fuse D_skip + silu(z); writes yg in bf16
__global__ __launch_bounds__(256) void scan_phase3(const float* __restrict__ dt,
                                                   const float* __restrict__ uc,
                                                   const float* __restrict__ xz,
                                                   const float* __restrict__ xdbl,
                                                   const float* __restrict__ A_log,
                                                   const float* __restrict__ D_skip,
                                                   const float* __restrict__ hinitG,
                                                   u16* __restrict__ ygb)
{
  __shared__ float dts[CT][16];
  __shared__ float us[CT][16];
  __shared__ float Bls[CT][16];
  __shared__ float Cls[CT][16];
  __shared__ float zs[CT][16];
  __shared__ float ys[CT][16];
  const int c = blockIdx.x, dblk = blockIdx.y, b = blockIdx.z;
  const int tid = threadIdx.x;
  const int n = tid & 15, dg = tid >> 4;
  const int d0 = dblk * 16, t0 = c * CT;
  for (int i = tid; i < CT * 16; i += 256) {
    int r = i >> 4, col = i & 15;
    size_t row = (size_t)(b * LL + t0 + r);
    size_t g = row * DIN + d0 + col;
    dts[r][col] = dt[g];
    us[r][col]  = uc[g];
    Bls[r][col] = xdbl[row * 64 + 32 + col];
    Cls[r][col] = xdbl[row * 64 + 48 + col];
    zs[r][col]  = xz[row * (2 * DIN) + DIN + d0 + col];
  }
  __syncthreads();
  const int d = d0 + dg;
  const float Ad = -__expf(A_log[d * NS + n]);
  const float Dd = D_skip[d];
  float h = hinitG[(size_t)c * (BB * DIN * NS) + (size_t)(b * DIN + d) * NS + n];
#pragma unroll 4
  for (int t = 0; t < CT; ++t) {
    float dtv = dts[t][dg];
    float ucv = us[t][dg];
    float a = __expf(dtv * Ad);
    h = fmaf(a, h, dtv * Bls[t][n] * ucv);
    float p = h * Cls[t][n];
    p += __shfl_xor(p, 1, 16);
    p += __shfl_xor(p, 2, 16);
    p += __shfl_xor(p, 4, 16);
    p += __shfl_xor(p, 8, 16);
    if (n == 0) {
      ys[t][dg] = fmaf(ucv, Dd, p) * siluf_(zs[t][dg]);
    }
  }
  __syncthreads();
  for (int i = tid; i < CT * 16; i += 256) {
    int r = i >> 4, col = i & 15;
    ygb[((size_t)(b * LL + t0 + r)) * DIN + d0 + col] = f2bf(ys[r][col]);
  }
}

// ---------------- LN1: r = layernorm(x - m)*g1 + b1, dual fp32+bf16 out ----------------
__global__ __launch_bounds__(256) void ln1_kernel(const float* __restrict__ x,
                                                  const float* __restrict__ m,
                                                  const float* __restrict__ g,
                                                  const float* __restrict__ b,
                                                  float* __restrict__ r,
                                                  u16* __restrict__ rbf)
{
  int row = blockIdx.x;
  int tid = threadIdx.x;
  size_t base = (size_t)row * DD;
  float2 xv = *(const float2*)&x[base + tid * 2];
  float2 mv = *(const float2*)&m[base + tid * 2];
  float v0 = xv.x - mv.x, v1 = xv.y - mv.y;
  float s = v0 + v1, ss = v0 * v0 + v1 * v1;
#pragma unroll
  for (int off = 32; off; off >>= 1) { s += __shfl_down(s, off, 64); ss += __shfl_down(ss, off, 64); }
  __shared__ float sm[8];
  int w = tid >> 6;
  if ((tid & 63) == 0) { sm[w] = s; sm[4 + w] = ss; }
  __syncthreads();
  float S = sm[0] + sm[1] + sm[2] + sm[3];
  float SS = sm[4] + sm[5] + sm[6] + sm[7];
  float mean = S * (1.f / DD);
  float var = SS * (1.f / DD) - mean * mean;
  float rstd = rsqrtf(var + 1e-5f);
  float2 gv = *(const float2*)&g[tid * 2];
  float2 bv = *(const float2*)&b[tid * 2];
  float2 o;
  o.x = (v0 - mean) * rstd * gv.x + bv.x;
  o.y = (v1 - mean) * rstd * gv.y + bv.y;
  *(float2*)&r[base + tid * 2] = o;
  u32 pk = (u32)f2bf(o.x) | ((u32)f2bf(o.y) << 16);
  *(u32*)&rbf[base + tid * 2] = pk;
}

// ---------------- final: out = layernorm(silu(r - ff)) * g2 + b2 + x ----------------
__global__ __launch_bounds__(256) void final_kernel(const float* __restrict__ r,
                                                    const float* __restrict__ ff,
                                                    const float* __restrict__ x,
                                                    const float* __restrict__ g,
                                                    const float* __restrict__ b,
                                                    float* __restrict__ out)
{
  int row = blockIdx.x;
  int tid = threadIdx.x;
  size_t base = (size_t)row * DD;
  float2 rv = *(const float2*)&r[base + tid * 2];
  float2 fv = *(const float2*)&ff[base + tid * 2];
  float v0 = rv.x - fv.x, v1 = rv.y - fv.y;
  v0 = siluf_(v0); v1 = siluf_(v1);
  float s = v0 + v1, ss = v0 * v0 + v1 * v1;
#pragma unroll
  for (int off = 32; off; off >>= 1) { s += __shfl_down(s, off, 64); ss += __shfl_down(ss, off, 64); }
  __shared__ float sm[8];
  int w = tid >> 6;
  if ((tid & 63) == 0) { sm[w] = s; sm[4 + w] = ss; }
  __syncthreads();
  float S = sm[0] + sm[1] + sm[2] + sm[3];
  float SS = sm[4] + sm[5] + sm[6] + sm[7];
  float mean = S * (1.f / DD);
  float var = SS * (1.f / DD) - mean * mean;
  float rstd = rsqrtf(var + 1e-5f);
  float2 gv = *(const float2*)&g[tid * 2];
  float2 bv = *(const float2*)&b[tid * 2];
  float2 xv = *(const float2*)&x[base + tid * 2];
  float2 o;
  o.x = (v0 - mean) * rstd * gv.x + bv.x + xv.x;
  o.y = (v1 - mean) * rstd * gv.y + bv.y + xv.y;
  *(float2*)&out[base + tid * 2] = o;
}

extern "C" void kernel_launch(void* const* d_in, const int* in_sizes, int n_in,
                              void* d_out, int out_size, void* d_ws, size_t ws_size,
                              hipStream_t stream)
{
  const float* x      = (const float*)d_in[0];
  const float* W_in   = (const float*)d_in[1];
  const float* conv_w = (const float*)d_in[2];
  const float* conv_b = (const float*)d_in[3];
  const float* W_xp   = (const float*)d_in[4];
  const float* W_dt   = (const float*)d_in[5];
  const float* b_dt   = (const float*)d_in[6];
  const float* A_log  = (const float*)d_in[7];
  const float* D_skip = (const float*)d_in[8];
  const float* W_out  = (const float*)d_in[9];
  const float* g1     = (const float*)d_in[10];
  const float* b1     = (const float*)d_in[11];
  const float* W_ff1  = (const float*)d_in[12];
  const float* b_ff1  = (const float*)d_in[13];
  const float* W_ff2  = (const float*)d_in[14];
  const float* b_ff2  = (const float*)d_in[15];
  const float* g2     = (const float*)d_in[16];
  const float* b2     = (const float*)d_in[17];
  float* out = (float*)d_out;

  float* ws = (float*)d_ws;
  // fp32 regions (float offsets)
  float* xz   = ws;                     // 4,194,304
  float* uc   = ws + 4194304;           // 2,097,152
  float* xdbl = ws + 6291456;           //   131,072
  float* dtb  = ws + 6422528;           // 2,097,152
  u16*   ygb  = (u16*)(ws + 8519680);   // 2,097,152 bf16 (1,048,576 f)
  float* mb   = ws + 9568256;           // 1,048,576
  float* rb   = ws + 10616832;          // 1,048,576
  float* big  = ws + 11665408;          // 1,572,864 (scan states, later bffh+brb)
  // overlays
  u16* bx     = (u16*)mb;               // dead before mb written (out_proj)
  u16* bW_in  = (u16*)(mb + 524288);
  u16* bW_out = (u16*)dtb;              // converted after scan (dtb dead)
  u16* bW_ff1 = (u16*)(dtb + 262144);
  u16* bW_ff2 = (u16*)(dtb + 524288);
  float* aprodG = big;                  // 524,288
  float* hlocG  = big + 524288;
  float* hinitG = big + 1048576;
  u16* bffh   = (u16*)big;              // after scan dead: 2,097,152 bf16
  u16* brb    = (u16*)(big + 1048576);  // 1,048,576 bf16

  // 1. casts for in_proj
  cvt_bf16<<<512, 256, 0, stream>>>(x, bx, ML * DD);
  cvt_bf16<<<512, 256, 0, stream>>>(W_in, bW_in, 2 * DIN * DD);
  // 2. in_proj (bf16 MFMA): xz = x @ W_in^T
  gemm_bf16<0, float><<<dim3(16, 16), 256, 0, stream>>>(bx, bW_in, nullptr, xz, ML, 2 * DIN, DD);
  // 3. conv + silu
  conv_silu<<<(ML * DIN) / 256, 256, 0, stream>>>(xz, conv_w, conv_b, uc);
  // 4. x_proj
  xproj_kernel<<<ML, 64, 0, stream>>>(uc, W_xp, xdbl);
  // 5. dt_proj + softplus
  dtproj_kernel<<<(ML * DIN) / 256, 256, 0, stream>>>(xdbl, W_dt, b_dt, dtb);
  // 6. chunked scan (phase3 emits bf16 yg)
  scan_phase1<<<dim3(NC, DIN / 16, BB), 256, 0, stream>>>(dtb, uc, xdbl, A_log, aprodG, hlocG);
  scan_phase2<<<(BB * DIN * NS) / 256, 256, 0, stream>>>(aprodG, hlocG, hinitG);
  scan_phase3<<<dim3(NC, DIN / 16, BB), 256, 0, stream>>>(dtb, uc, xz, xdbl, A_log, D_skip,
                                                          hinitG, ygb);
  // 7. weight casts (dtb now dead)
  cvt_bf16<<<256, 256, 0, stream>>>(W_out, bW_out, DD * DIN);
  cvt_bf16<<<256, 256, 0, stream>>>(W_ff1, bW_ff1, 2 * DD * DD);
  cvt_bf16<<<256, 256, 0, stream>>>(W_ff2, bW_ff2, DD * DIN);
  // 8. out_proj: mb = yg @ W_out^T
  gemm_bf16<0, float><<<dim3(4, 16), 256, 0, stream>>>(ygb, bW_out, nullptr, mb, ML, DD, DIN);
  // 9. LN1 (fp32 + bf16 out)
  ln1_kernel<<<ML, 256, 0, stream>>>(x, mb, g1, b1, rb, brb);
  // 10. ff1 + bias + gelu -> bf16
  gemm_bf16<2, u16><<<dim3(8, 16), 256, 0, stream>>>(brb, bW_ff1, b_ff1, bffh, ML, DIN, DD);
  // 11. ff2 + bias -> mb
  gemm_bf16<1, float><<<dim3(4, 16), 256, 0, stream>>>(bffh, bW_ff2, b_ff2, mb, ML, DD, DIN);
  // 12. final
  final_kernel<<<ML, 256, 0, stream>>>(rb, mb, x, g2, b2, out);
}

// Round 4
// 237.036 us; speedup vs baseline: 4.3071x; 1.1660x over previous
//
#include <hip/hip_runtime.h>
#include <math.h>

#define BB 2
#define LL 1024
#define DD 512
#define DIN 1024      // d_inner
#define NS 16         // d_state
#define RNK 32        // dt_rank
#define ML (BB*LL)    // 2048 rows
#define CT 64         // scan chunk length
#define NC (LL/CT)    // 16 chunks

typedef unsigned short u16;
typedef unsigned int u32;

__device__ __forceinline__ float sigmoidf_(float v) { return 1.f / (1.f + __expf(-v)); }
__device__ __forceinline__ float siluf_(float v) { return v * sigmoidf_(v); }
__device__ __forceinline__ u16 f2bf(float f) {
  union { float f; u32 u; } c; c.f = f;
  u32 r = c.u + 0x7fffu + ((c.u >> 16) & 1u);
  return (u16)(r >> 16);
}

// ---------------- fp32 -> bf16 cast (n multiple of 2048) ----------------
__global__ __launch_bounds__(256) void cvt_bf16(const float* __restrict__ in,
                                                u16* __restrict__ out, int n)
{
  int i = (blockIdx.x * 256 + threadIdx.x) * 8;
  if (i >= n) return;
  float4 v0 = *(const float4*)&in[i];
  float4 v1 = *(const float4*)&in[i + 4];
  union { u16 u[8]; uint4 v; } p;
  p.u[0] = f2bf(v0.x); p.u[1] = f2bf(v0.y); p.u[2] = f2bf(v0.z); p.u[3] = f2bf(v0.w);
  p.u[4] = f2bf(v1.x); p.u[5] = f2bf(v1.y); p.u[6] = f2bf(v1.z); p.u[7] = f2bf(v1.w);
  *(uint4*)&out[i] = p.v;
}

// ---------------- bf16 MFMA GEMM: C[M,N] = A[M,K] @ W[N,K]^T ----------------
// EPI: 0 none, 1 +bias, 2 +bias+gelu.  OT: float or u16 (bf16 out)
using bf16x8 = __attribute__((ext_vector_type(8))) short;
using f32x4  = __attribute__((ext_vector_type(4))) float;

template<int EPI, typename OT>
__global__ __launch_bounds__(256) void gemm_bf16(const u16* __restrict__ A,
                                                 const u16* __restrict__ W,
                                                 const float* __restrict__ bias,
                                                 OT* __restrict__ C,
                                                 int M, int N, int K)
{
  __shared__ u16 As[128][40];   // pad to 40 (80B row): ~2-way bank alias max
  __shared__ u16 Bs[128][40];
  const int bm = blockIdx.y * 128, bn = blockIdx.x * 128;
  const int tid = threadIdx.x;
  const int w = tid >> 6, l = tid & 63;
  const int wr = w >> 1, wc = w & 1;       // wave -> 64x64 quadrant
  const int lr = l & 15, lh = l >> 4;      // frag row, k-half
  const int sr0 = tid >> 2, sc0 = tid & 3; // staging: row, 16B-chunk col
  f32x4 acc[4][4] = {};
  for (int k0 = 0; k0 < K; k0 += 32) {
    uint4 a0 = *(const uint4*)&A[(size_t)(bm + sr0) * K + k0 + sc0 * 8];
    uint4 a1 = *(const uint4*)&A[(size_t)(bm + sr0 + 64) * K + k0 + sc0 * 8];
    uint4 b0 = *(const uint4*)&W[(size_t)(bn + sr0) * K + k0 + sc0 * 8];
    uint4 b1 = *(const uint4*)&W[(size_t)(bn + sr0 + 64) * K + k0 + sc0 * 8];
    __syncthreads();
    *(uint4*)&As[sr0][sc0 * 8] = a0;
    *(uint4*)&As[sr0 + 64][sc0 * 8] = a1;
    *(uint4*)&Bs[sr0][sc0 * 8] = b0;
    *(uint4*)&Bs[sr0 + 64][sc0 * 8] = b1;
    __syncthreads();
    bf16x8 af[4], bfr[4];
#pragma unroll
    for (int i = 0; i < 4; ++i) af[i]  = *(bf16x8*)&As[wr * 64 + i * 16 + lr][lh * 8];
#pragma unroll
    for (int j = 0; j < 4; ++j) bfr[j] = *(bf16x8*)&Bs[wc * 64 + j * 16 + lr][lh * 8];
#pragma unroll
    for (int i = 0; i < 4; ++i)
#pragma unroll
      for (int j = 0; j < 4; ++j)
        acc[i][j] = __builtin_amdgcn_mfma_f32_16x16x32_bf16(af[i], bfr[j], acc[i][j], 0, 0, 0);
  }
#pragma unroll
  for (int i = 0; i < 4; ++i) {
#pragma unroll
    for (int j = 0; j < 4; ++j) {
      int col = bn + wc * 64 + j * 16 + lr;
      float bv = (EPI >= 1) ? bias[col] : 0.f;
#pragma unroll
      for (int r = 0; r < 4; ++r) {
        int row = bm + wr * 64 + i * 16 + lh * 4 + r;
        float t = acc[i][j][r] + bv;
        if (EPI == 2) t = 0.5f * t * (1.f + erff(t * 0.70710678118654752f));
        if constexpr (sizeof(OT) == 2) C[(size_t)row * N + col] = (OT)f2bf(t);
        else                           C[(size_t)row * N + col] = (OT)t;
      }
    }
  }
}

// ---------------- x_proj via MFMA: xdbl[M,64] = ucb[M,K=1024] @ Wxb[64,K]^T ----------------
__global__ __launch_bounds__(256) void xproj_mfma(const u16* __restrict__ A,
                                                  const u16* __restrict__ W,
                                                  float* __restrict__ C)
{
  __shared__ u16 As[128][40];
  __shared__ u16 Bs[64][40];
  const int bm = blockIdx.x * 128;
  const int tid = threadIdx.x;
  const int w = tid >> 6, l = tid & 63;
  const int lr = l & 15, lh = l >> 4;
  const int sr0 = tid >> 2, sc0 = tid & 3;
  f32x4 acc[2][4] = {};
  for (int k0 = 0; k0 < DIN; k0 += 32) {
    uint4 a0 = *(const uint4*)&A[(size_t)(bm + sr0) * DIN + k0 + sc0 * 8];
    uint4 a1 = *(const uint4*)&A[(size_t)(bm + sr0 + 64) * DIN + k0 + sc0 * 8];
    uint4 b0;
    if (sr0 < 64) b0 = *(const uint4*)&W[(size_t)sr0 * DIN + k0 + sc0 * 8];
    __syncthreads();
    *(uint4*)&As[sr0][sc0 * 8] = a0;
    *(uint4*)&As[sr0 + 64][sc0 * 8] = a1;
    if (sr0 < 64) *(uint4*)&Bs[sr0][sc0 * 8] = b0;
    __syncthreads();
    bf16x8 af[2], bfr[4];
#pragma unroll
    for (int i = 0; i < 2; ++i) af[i]  = *(bf16x8*)&As[w * 32 + i * 16 + lr][lh * 8];
#pragma unroll
    for (int j = 0; j < 4; ++j) bfr[j] = *(bf16x8*)&Bs[j * 16 + lr][lh * 8];
#pragma unroll
    for (int i = 0; i < 2; ++i)
#pragma unroll
      for (int j = 0; j < 4; ++j)
        acc[i][j] = __builtin_amdgcn_mfma_f32_16x16x32_bf16(af[i], bfr[j], acc[i][j], 0, 0, 0);
  }
#pragma unroll
  for (int i = 0; i < 2; ++i)
#pragma unroll
    for (int j = 0; j < 4; ++j) {
      int col = j * 16 + lr;
#pragma unroll
      for (int r = 0; r < 4; ++r) {
        int row = bm + w * 32 + i * 16 + lh * 4 + r;
        C[(size_t)row * 64 + col] = acc[i][j][r];
      }
    }
}

// ---------------- depthwise causal conv (K=4) + SiLU; dual fp32+bf16 out ----------------
__global__ __launch_bounds__(256) void conv_silu(const float* __restrict__ xz,
                                                 const float* __restrict__ conv_w,
                                                 const float* __restrict__ conv_b,
                                                 float* __restrict__ uc,
                                                 u16* __restrict__ ucb)
{
  int idx = blockIdx.x * 256 + threadIdx.x;
  int d = idx & (DIN - 1);
  int bl = idx >> 10;
  int l = bl & (LL - 1);
  int b = bl >> 10;
  float acc = conv_b[d];
#pragma unroll
  for (int k = 0; k < 4; ++k) {
    int ls = l - 3 + k;
    float uv = (ls >= 0) ? xz[((size_t)(b * LL + ls)) * (2 * DIN) + d] : 0.f;
    acc = fmaf(uv, conv_w[d * 4 + k], acc);
  }
  float s = siluf_(acc);
  uc[idx] = s;
  ucb[idx] = f2bf(s);
}

// ---------------- dt = softplus(dt_r @ W_dt^T + b_dt) ----------------
__global__ __launch_bounds__(256) void dtproj_kernel(const float* __restrict__ xdbl,
                                                     const float* __restrict__ Wdt,
                                                     const float* __restrict__ bdt,
                                                     float* __restrict__ dt)
{
  int idx = blockIdx.x * 256 + threadIdx.x;
  int d = idx & (DIN - 1);
  int m = idx >> 10;
  const float4* xr = (const float4*)&xdbl[m * 64];
  const float4* wr = (const float4*)&Wdt[(size_t)d * RNK];
  float acc = bdt[d];
#pragma unroll
  for (int q = 0; q < 8; ++q) {
    float4 xv = xr[q], wv = wr[q];
    acc = fmaf(xv.x, wv.x, acc);
    acc = fmaf(xv.y, wv.y, acc);
    acc = fmaf(xv.z, wv.z, acc);
    acc = fmaf(xv.w, wv.w, acc);
  }
  float sp = fmaxf(acc, 0.f) + log1pf(__expf(-fabsf(acc)));
  dt[idx] = sp;
}

// ================= chunked selective scan =================
__global__ __launch_bounds__(256) void scan_phase1(const float* __restrict__ dt,
                                                   const float* __restrict__ uc,
                                                   const float* __restrict__ xdbl,
                                                   const float* __restrict__ A_log,
                                                   float* __restrict__ aprodG,
                                                   float* __restrict__ hlocG)
{
  __shared__ float dts[CT][16];
  __shared__ float us[CT][16];
  __shared__ float Bls[CT][16];
  const int c = blockIdx.x, dblk = blockIdx.y, b = blockIdx.z;
  const int tid = threadIdx.x;
  const int n = tid & 15, dg = tid >> 4;
  const int d0 = dblk * 16, t0 = c * CT;
  for (int i = tid; i < CT * 16; i += 256) {
    int r = i >> 4, col = i & 15;
    size_t row = (size_t)(b * LL + t0 + r);
    size_t g = row * DIN + d0 + col;
    dts[r][col] = dt[g];
    us[r][col]  = uc[g];
    Bls[r][col] = xdbl[row * 64 + 32 + col];
  }
  __syncthreads();
  const int d = d0 + dg;
  const float Ad = -__expf(A_log[d * NS + n]);
  float h = 0.f, ap = 1.f;
#pragma unroll 8
  for (int t = 0; t < CT; ++t) {
    float dtv = dts[t][dg];
    float a = __expf(dtv * Ad);
    h = fmaf(a, h, dtv * Bls[t][n] * us[t][dg]);
    ap *= a;
  }
  size_t o = (size_t)c * (BB * DIN * NS) + (size_t)(b * DIN + d) * NS + n;
  aprodG[o] = ap;
  hlocG[o] = h;
}

__global__ __launch_bounds__(256) void scan_phase2(const float* __restrict__ aprodG,
                                                   const float* __restrict__ hlocG,
                                                   float* __restrict__ hinitG)
{
  const int idx = blockIdx.x * 256 + threadIdx.x;
  const int STRIDE = BB * DIN * NS;
  float ap[NC], hl[NC];
#pragma unroll
  for (int c = 0; c < NC; ++c) {
    ap[c] = aprodG[c * STRIDE + idx];
    hl[c] = hlocG[c * STRIDE + idx];
  }
  float H = 0.f;
#pragma unroll
  for (int c = 0; c < NC; ++c) {
    hinitG[c * STRIDE + idx] = H;
    H = fmaf(ap[c], H, hl[c]);
  }
}

// phase 3: replay chunk, reduce over n, fuse D_skip + silu(z); writes yg in bf16
__global__ __launch_bounds__(256) void scan_phase3(const float* __restrict__ dt,
                                                   const float* __restrict__ uc,
                                                   const float* __restrict__ xz,
                                                   const float* __restrict__ xdbl,
                                                   const float* __restrict__ A_log,
                                                   const float* __restrict__ D_skip,
                                                   const float* __restrict__ hinitG,
                                                   u16* __restrict__ ygb)
{
  __shared__ float dts[CT][16];
  __shared__ float us[CT][16];
  __shared__ float Bls[CT][16];
  __shared__ float Cls[CT][16];
  __shared__ float zs[CT][16];
  __shared__ float ys[CT][16];
  const int c = blockIdx.x, dblk = blockIdx.y, b = blockIdx.z;
  const int tid = threadIdx.x;
  const int n = tid & 15, dg = tid >> 4;
  const int d0 = dblk * 16, t0 = c * CT;
  for (int i = tid; i < CT * 16; i += 256) {
    int r = i >> 4, col = i & 15;
    size_t row = (size_t)(b * LL + t0 + r);
    size_t g = row * DIN + d0 + col;
    dts[r][col] = dt[g];
    us[r][col]  = uc[g];
    Bls[r][col] = xdbl[row * 64 + 32 + col];
    Cls[r][col] = xdbl[row * 64 + 48 + col];
    zs[r][col]  = xz[row * (2 * DIN) + DIN + d0 + col];
  }
  __syncthreads();
  const int d = d0 + dg;
  const float Ad = -__expf(A_log[d * NS + n]);
  const float Dd = D_skip[d];
  float h = hinitG[(size_t)c * (BB * DIN * NS) + (size_t)(b * DIN + d) * NS + n];
#pragma unroll 4
  for (int t = 0; t < CT; ++t) {
    float dtv = dts[t][dg];
    float ucv = us[t][dg];
    float a = __expf(dtv * Ad);
    h = fmaf(a, h, dtv * Bls[t][n] * ucv);
    float p = h * Cls[t][n];
    p += __shfl_xor(p, 1, 16);
    p += __shfl_xor(p, 2, 16);
    p += __shfl_xor(p, 4, 16);
    p += __shfl_xor(p, 8, 16);
    if (n == 0) {
      ys[t][dg] = fmaf(ucv, Dd, p) * siluf_(zs[t][dg]);
    }
  }
  __syncthreads();
  for (int i = tid; i < CT * 16; i += 256) {
    int r = i >> 4, col = i & 15;
    ygb[((size_t)(b * LL + t0 + r)) * DIN + d0 + col] = f2bf(ys[r][col]);
  }
}

// ---------------- LN1: r = layernorm(x - m)*g1 + b1, dual fp32+bf16 out ----------------
__global__ __launch_bounds__(256) void ln1_kernel(const float* __restrict__ x,
                                                  const float* __restrict__ m,
                                                  const float* __restrict__ g,
                                                  const float* __restrict__ b,
                                                  float* __restrict__ r,
                                                  u16* __restrict__ rbf)
{
  int row = blockIdx.x;
  int tid = threadIdx.x;
  size_t base = (size_t)row * DD;
  float2 xv = *(const float2*)&x[base + tid * 2];
  float2 mv = *(const float2*)&m[base + tid * 2];
  float v0 = xv.x - mv.x, v1 = xv.y - mv.y;
  float s = v0 + v1, ss = v0 * v0 + v1 * v1;
#pragma unroll
  for (int off = 32; off; off >>= 1) { s += __shfl_down(s, off, 64); ss += __shfl_down(ss, off, 64); }
  __shared__ float sm[8];
  int w = tid >> 6;
  if ((tid & 63) == 0) { sm[w] = s; sm[4 + w] = ss; }
  __syncthreads();
  float S = sm[0] + sm[1] + sm[2] + sm[3];
  float SS = sm[4] + sm[5] + sm[6] + sm[7];
  float mean = S * (1.f / DD);
  float var = SS * (1.f / DD) - mean * mean;
  float rstd = rsqrtf(var + 1e-5f);
  float2 gv = *(const float2*)&g[tid * 2];
  float2 bv = *(const float2*)&b[tid * 2];
  float2 o;
  o.x = (v0 - mean) * rstd * gv.x + bv.x;
  o.y = (v1 - mean) * rstd * gv.y + bv.y;
  *(float2*)&r[base + tid * 2] = o;
  u32 pk = (u32)f2bf(o.x) | ((u32)f2bf(o.y) << 16);
  *(u32*)&rbf[base + tid * 2] = pk;
}

// ---------------- final: out = layernorm(silu(r - ff)) * g2 + b2 + x ----------------
__global__ __launch_bounds__(256) void final_kernel(const float* __restrict__ r,
                                                    const float* __restrict__ ff,
                                                    const float* __restrict__ x,
                                                    const float* __restrict__ g,
                                                    const float* __restrict__ b,
                                                    float* __restrict__ out)
{
  int row = blockIdx.x;
  int tid = threadIdx.x;
  size_t base = (size_t)row * DD;
  float2 rv = *(const float2*)&r[base + tid * 2];
  float2 fv = *(const float2*)&ff[base + tid * 2];
  float v0 = rv.x - fv.x, v1 = rv.y - fv.y;
  v0 = siluf_(v0); v1 = siluf_(v1);
  float s = v0 + v1, ss = v0 * v0 + v1 * v1;
#pragma unroll
  for (int off = 32; off; off >>= 1) { s += __shfl_down(s, off, 64); ss += __shfl_down(ss, off, 64); }
  __shared__ float sm[8];
  int w = tid >> 6;
  if ((tid & 63) == 0) { sm[w] = s; sm[4 + w] = ss; }
  __syncthreads();
  float S = sm[0] + sm[1] + sm[2] + sm[3];
  float SS = sm[4] + sm[5] + sm[6] + sm[7];
  float mean = S * (1.f / DD);
  float var = SS * (1.f / DD) - mean * mean;
  float rstd = rsqrtf(var + 1e-5f);
  float2 gv = *(const float2*)&g[tid * 2];
  float2 bv = *(const float2*)&b[tid * 2];
  float2 xv = *(const float2*)&x[base + tid * 2];
  float2 o;
  o.x = (v0 - mean) * rstd * gv.x + bv.x + xv.x;
  o.y = (v1 - mean) * rstd * gv.y + bv.y + xv.y;
  *(float2*)&out[base + tid * 2] = o;
}

extern "C" void kernel_launch(void* const* d_in, const int* in_sizes, int n_in,
                              void* d_out, int out_size, void* d_ws, size_t ws_size,
                              hipStream_t stream)
{
  const float* x      = (const float*)d_in[0];
  const float* W_in   = (const float*)d_in[1];
  const float* conv_w = (const float*)d_in[2];
  const float* conv_b = (const float*)d_in[3];
  const float* W_xp   = (const float*)d_in[4];
  const float* W_dt   = (const float*)d_in[5];
  const float* b_dt   = (const float*)d_in[6];
  const float* A_log  = (const float*)d_in[7];
  const float* D_skip = (const float*)d_in[8];
  const float* W_out  = (const float*)d_in[9];
  const float* g1     = (const float*)d_in[10];
  const float* b1     = (const float*)d_in[11];
  const float* W_ff1  = (const float*)d_in[12];
  const float* b_ff1  = (const float*)d_in[13];
  const float* W_ff2  = (const float*)d_in[14];
  const float* b_ff2  = (const float*)d_in[15];
  const float* g2     = (const float*)d_in[16];
  const float* b2     = (const float*)d_in[17];
  float* out = (float*)d_out;

  float* ws = (float*)d_ws;
  // fp32 regions (float offsets)
  float* xz   = ws;                     // 4,194,304
  float* uc   = ws + 4194304;           // 2,097,152
  float* xdbl = ws + 6291456;           //   131,072
  float* dtb  = ws + 6422528;           // 2,097,152
  u16*   ygb  = (u16*)(ws + 8519680);   // 2,097,152 bf16 (1,048,576 f)
  float* mb   = ws + 9568256;           // 1,048,576
  float* rb   = ws + 10616832;          // 1,048,576
  float* big  = ws + 11665408;          // 1,572,864 (scan states, later bffh+brb)
  u16*   ucb  = (u16*)(ws + 13238272);  // 2,097,152 bf16 (1,048,576 f)
  u16*   bWxp = (u16*)(ws + 14286848);  // 65,536 bf16 (32,768 f)
  // overlays
  u16* bx     = (u16*)mb;               // dead before mb written (out_proj)
  u16* bW_in  = (u16*)(mb + 524288);
  u16* bW_out = (u16*)dtb;              // converted after scan (dtb dead)
  u16* bW_ff1 = (u16*)(dtb + 262144);
  u16* bW_ff2 = (u16*)(dtb + 524288);
  float* aprodG = big;                  // 524,288
  float* hlocG  = big + 524288;
  float* hinitG = big + 1048576;
  u16* bffh   = (u16*)big;              // after scan dead: 2,097,152 bf16
  u16* brb    = (u16*)(big + 1048576);  // 1,048,576 bf16

  // 1. casts for in_proj / x_proj
  cvt_bf16<<<512, 256, 0, stream>>>(x, bx, ML * DD);
  cvt_bf16<<<512, 256, 0, stream>>>(W_in, bW_in, 2 * DIN * DD);
  cvt_bf16<<<32, 256, 0, stream>>>(W_xp, bWxp, 64 * DIN);
  // 2. in_proj (bf16 MFMA): xz = x @ W_in^T
  gemm_bf16<0, float><<<dim3(16, 16), 256, 0, stream>>>(bx, bW_in, nullptr, xz, ML, 2 * DIN, DD);
  // 3. conv + silu (fp32 + bf16 out)
  conv_silu<<<(ML * DIN) / 256, 256, 0, stream>>>(xz, conv_w, conv_b, uc, ucb);
  // 4. x_proj (bf16 MFMA)
  xproj_mfma<<<ML / 128, 256, 0, stream>>>(ucb, bWxp, xdbl);
  // 5. dt_proj + softplus
  dtproj_kernel<<<(ML * DIN) / 256, 256, 0, stream>>>(xdbl, W_dt, b_dt, dtb);
  // 6. chunked scan (phase3 emits bf16 yg)
  scan_phase1<<<dim3(NC, DIN / 16, BB), 256, 0, stream>>>(dtb, uc, xdbl, A_log, aprodG, hlocG);
  scan_phase2<<<(BB * DIN * NS) / 256, 256, 0, stream>>>(aprodG, hlocG, hinitG);
  scan_phase3<<<dim3(NC, DIN / 16, BB), 256, 0, stream>>>(dtb, uc, xz, xdbl, A_log, D_skip,
                                                          hinitG, ygb);
  // 7. weight casts (dtb now dead)
  cvt_bf16<<<256, 256, 0, stream>>>(W_out, bW_out, DD * DIN);
  cvt_bf16<<<256, 256, 0, stream>>>(W_ff1, bW_ff1, 2 * DD * DD);
  cvt_bf16<<<256, 256, 0, stream>>>(W_ff2, bW_ff2, DD * DIN);
  // 8. out_proj: mb = yg @ W_out^T
  gemm_bf16<0, float><<<dim3(4, 16), 256, 0, stream>>>(ygb, bW_out, nullptr, mb, ML, DD, DIN);
  // 9. LN1 (fp32 + bf16 out)
  ln1_kernel<<<ML, 256, 0, stream>>>(x, mb, g1, b1, rb, brb);
  // 10. ff1 + bias + gelu -> bf16
  gemm_bf16<2, u16><<<dim3(8, 16), 256, 0, stream>>>(brb, bW_ff1, b_ff1, bffh, ML, DIN, DD);
  // 11. ff2 + bias -> mb
  gemm_bf16<1, float><<<dim3(4, 16), 256, 0, stream>>>(bffh, bW_ff2, b_ff2, mb, ML, DD, DIN);
  // 12. final
  final_kernel<<<ML, 256, 0, stream>>>(rb, mb, x, g2, b2, out);
}

// Round 5
// 221.272 us; speedup vs baseline: 4.6140x; 1.0712x over previous
//
#include <hip/hip_runtime.h>
#include <math.h>

#define BB 2
#define LL 1024
#define DD 512
#define DIN 1024      // d_inner
#define NS 16         // d_state
#define RNK 32        // dt_rank
#define ML (BB*LL)    // 2048 rows
#define CT 16         // scan chunk length
#define NC (LL/CT)    // 64 chunks
#define BDIN (BB*DIN) // 2048

typedef unsigned short u16;
typedef unsigned int u32;

__device__ __forceinline__ float sigmoidf_(float v) { return 1.f / (1.f + __expf(-v)); }
__device__ __forceinline__ float siluf_(float v) { return v * sigmoidf_(v); }
__device__ __forceinline__ u16 f2bf(float f) {
  union { float f; u32 u; } c; c.f = f;
  u32 r = c.u + 0x7fffu + ((c.u >> 16) & 1u);
  return (u16)(r >> 16);
}
__device__ __forceinline__ float bf2f(u16 x) {
  union { u32 u; float f; } c; c.u = (u32)x << 16;
  return c.f;
}

// ---------------- fp32 -> bf16 cast (n multiple of 2048) ----------------
__global__ __launch_bounds__(256) void cvt_bf16(const float* __restrict__ in,
                                                u16* __restrict__ out, int n)
{
  int i = (blockIdx.x * 256 + threadIdx.x) * 8;
  if (i >= n) return;
  float4 v0 = *(const float4*)&in[i];
  float4 v1 = *(const float4*)&in[i + 4];
  union { u16 u[8]; uint4 v; } p;
  p.u[0] = f2bf(v0.x); p.u[1] = f2bf(v0.y); p.u[2] = f2bf(v0.z); p.u[3] = f2bf(v0.w);
  p.u[4] = f2bf(v1.x); p.u[5] = f2bf(v1.y); p.u[6] = f2bf(v1.z); p.u[7] = f2bf(v1.w);
  *(uint4*)&out[i] = p.v;
}

// ---------------- bf16 MFMA GEMM: C[M,N] = A[M,K] @ W[N,K]^T ----------------
using bf16x8 = __attribute__((ext_vector_type(8))) short;
using f32x4  = __attribute__((ext_vector_type(4))) float;

template<int EPI, typename OT>
__global__ __launch_bounds__(256) void gemm_bf16(const u16* __restrict__ A,
                                                 const u16* __restrict__ W,
                                                 const float* __restrict__ bias,
                                                 OT* __restrict__ C,
                                                 int M, int N, int K)
{
  __shared__ u16 As[128][40];
  __shared__ u16 Bs[128][40];
  const int bm = blockIdx.y * 128, bn = blockIdx.x * 128;
  const int tid = threadIdx.x;
  const int w = tid >> 6, l = tid & 63;
  const int wr = w >> 1, wc = w & 1;
  const int lr = l & 15, lh = l >> 4;
  const int sr0 = tid >> 2, sc0 = tid & 3;
  f32x4 acc[4][4] = {};
  for (int k0 = 0; k0 < K; k0 += 32) {
    uint4 a0 = *(const uint4*)&A[(size_t)(bm + sr0) * K + k0 + sc0 * 8];
    uint4 a1 = *(const uint4*)&A[(size_t)(bm + sr0 + 64) * K + k0 + sc0 * 8];
    uint4 b0 = *(const uint4*)&W[(size_t)(bn + sr0) * K + k0 + sc0 * 8];
    uint4 b1 = *(const uint4*)&W[(size_t)(bn + sr0 + 64) * K + k0 + sc0 * 8];
    __syncthreads();
    *(uint4*)&As[sr0][sc0 * 8] = a0;
    *(uint4*)&As[sr0 + 64][sc0 * 8] = a1;
    *(uint4*)&Bs[sr0][sc0 * 8] = b0;
    *(uint4*)&Bs[sr0 + 64][sc0 * 8] = b1;
    __syncthreads();
    bf16x8 af[4], bfr[4];
#pragma unroll
    for (int i = 0; i < 4; ++i) af[i]  = *(bf16x8*)&As[wr * 64 + i * 16 + lr][lh * 8];
#pragma unroll
    for (int j = 0; j < 4; ++j) bfr[j] = *(bf16x8*)&Bs[wc * 64 + j * 16 + lr][lh * 8];
#pragma unroll
    for (int i = 0; i < 4; ++i)
#pragma unroll
      for (int j = 0; j < 4; ++j)
        acc[i][j] = __builtin_amdgcn_mfma_f32_16x16x32_bf16(af[i], bfr[j], acc[i][j], 0, 0, 0);
  }
#pragma unroll
  for (int i = 0; i < 4; ++i) {
#pragma unroll
    for (int j = 0; j < 4; ++j) {
      int col = bn + wc * 64 + j * 16 + lr;
      float bv = (EPI >= 1) ? bias[col] : 0.f;
#pragma unroll
      for (int r = 0; r < 4; ++r) {
        int row = bm + wr * 64 + i * 16 + lh * 4 + r;
        float t = acc[i][j][r] + bv;
        if (EPI == 2) t = 0.5f * t * (1.f + erff(t * 0.70710678118654752f));
        if constexpr (sizeof(OT) == 2) C[(size_t)row * N + col] = (OT)f2bf(t);
        else                           C[(size_t)row * N + col] = (OT)t;
      }
    }
  }
}

// ---------------- x_proj via MFMA: xdbl[M,64] = ucb @ Wxb^T ----------------
__global__ __launch_bounds__(256) void xproj_mfma(const u16* __restrict__ A,
                                                  const u16* __restrict__ W,
                                                  float* __restrict__ C)
{
  __shared__ u16 As[128][40];
  __shared__ u16 Bs[64][40];
  const int bm = blockIdx.x * 128;
  const int tid = threadIdx.x;
  const int w = tid >> 6, l = tid & 63;
  const int lr = l & 15, lh = l >> 4;
  const int sr0 = tid >> 2, sc0 = tid & 3;
  f32x4 acc[2][4] = {};
  for (int k0 = 0; k0 < DIN; k0 += 32) {
    uint4 a0 = *(const uint4*)&A[(size_t)(bm + sr0) * DIN + k0 + sc0 * 8];
    uint4 a1 = *(const uint4*)&A[(size_t)(bm + sr0 + 64) * DIN + k0 + sc0 * 8];
    uint4 b0;
    if (sr0 < 64) b0 = *(const uint4*)&W[(size_t)sr0 * DIN + k0 + sc0 * 8];
    __syncthreads();
    *(uint4*)&As[sr0][sc0 * 8] = a0;
    *(uint4*)&As[sr0 + 64][sc0 * 8] = a1;
    if (sr0 < 64) *(uint4*)&Bs[sr0][sc0 * 8] = b0;
    __syncthreads();
    bf16x8 af[2], bfr[4];
#pragma unroll
    for (int i = 0; i < 2; ++i) af[i]  = *(bf16x8*)&As[w * 32 + i * 16 + lr][lh * 8];
#pragma unroll
    for (int j = 0; j < 4; ++j) bfr[j] = *(bf16x8*)&Bs[j * 16 + lr][lh * 8];
#pragma unroll
    for (int i = 0; i < 2; ++i)
#pragma unroll
      for (int j = 0; j < 4; ++j)
        acc[i][j] = __builtin_amdgcn_mfma_f32_16x16x32_bf16(af[i], bfr[j], acc[i][j], 0, 0, 0);
  }
#pragma unroll
  for (int i = 0; i < 2; ++i)
#pragma unroll
    for (int j = 0; j < 4; ++j) {
      int col = j * 16 + lr;
#pragma unroll
      for (int r = 0; r < 4; ++r) {
        int row = bm + w * 32 + i * 16 + lh * 4 + r;
        C[(size_t)row * 64 + col] = acc[i][j][r];
      }
    }
}

// ---------------- depthwise causal conv (K=4) + SiLU -> bf16 only ----------------
__global__ __launch_bounds__(256) void conv_silu(const float* __restrict__ xz,
                                                 const float* __restrict__ conv_w,
                                                 const float* __restrict__ conv_b,
                                                 u16* __restrict__ ucb)
{
  int idx = blockIdx.x * 256 + threadIdx.x;
  int d = idx & (DIN - 1);
  int bl = idx >> 10;
  int l = bl & (LL - 1);
  int b = bl >> 10;
  float acc = conv_b[d];
#pragma unroll
  for (int k = 0; k < 4; ++k) {
    int ls = l - 3 + k;
    float uv = (ls >= 0) ? xz[((size_t)(b * LL + ls)) * (2 * DIN) + d] : 0.f;
    acc = fmaf(uv, conv_w[d * 4 + k], acc);
  }
  ucb[idx] = f2bf(siluf_(acc));
}

// ---------------- dt = softplus(dt_r @ W_dt^T + b_dt) ----------------
__global__ __launch_bounds__(256) void dtproj_kernel(const float* __restrict__ xdbl,
                                                     const float* __restrict__ Wdt,
                                                     const float* __restrict__ bdt,
                                                     float* __restrict__ dt)
{
  int idx = blockIdx.x * 256 + threadIdx.x;
  int d = idx & (DIN - 1);
  int m = idx >> 10;
  const float4* xr = (const float4*)&xdbl[m * 64];
  const float4* wr = (const float4*)&Wdt[(size_t)d * RNK];
  float acc = bdt[d];
#pragma unroll
  for (int q = 0; q < 8; ++q) {
    float4 xv = xr[q], wv = wr[q];
    acc = fmaf(xv.x, wv.x, acc);
    acc = fmaf(xv.y, wv.y, acc);
    acc = fmaf(xv.z, wv.z, acc);
    acc = fmaf(xv.w, wv.w, acc);
  }
  float sp = fmaxf(acc, 0.f) + log1pf(__expf(-fabsf(acc)));
  dt[idx] = sp;
}

// ================= chunked selective scan, register-state design =================
// thread = one d, 16 n-states in VGPRs. state layout: [c][n][b*DIN+d]

// phase 1: per-chunk local scan + decay product exp(A*sum(dt))
__global__ __launch_bounds__(256) void scan_p1(const float* __restrict__ dt,
                                               const u16* __restrict__ ucb,
                                               const float* __restrict__ xdbl,
                                               const float* __restrict__ A_log,
                                               float* __restrict__ apG,
                                               float* __restrict__ hG)
{
  __shared__ float dts[CT][256];
  __shared__ float us[CT][256];
  __shared__ float Bs[CT][NS];
  const int d0 = blockIdx.x * 256, c = blockIdx.y, b = blockIdx.z;
  const int tid = threadIdx.x;
  const int t0 = c * CT;
  for (int i = tid; i < CT * 64; i += 256) {          // 1024 float4-slots
    int r = i >> 6, col = (i & 63) * 4;
    size_t row = (size_t)(b * LL + t0 + r);
    *(float4*)&dts[r][col] = *(const float4*)&dt[row * DIN + d0 + col];
    ushort4 uv = *(const ushort4*)&ucb[row * DIN + d0 + col];
    float4 uf = { bf2f(uv.x), bf2f(uv.y), bf2f(uv.z), bf2f(uv.w) };
    *(float4*)&us[r][col] = uf;
  }
  { int r = tid >> 4, n = tid & 15;
    Bs[r][n] = xdbl[(size_t)(b * LL + t0 + r) * 64 + 32 + n]; }
  __syncthreads();
  const int d = d0 + tid;
  float Ad[NS];
#pragma unroll
  for (int n = 0; n < NS; ++n) Ad[n] = -__expf(A_log[d * NS + n]);
  float h[NS] = {};
  float sdt = 0.f;
#pragma unroll 4
  for (int t = 0; t < CT; ++t) {
    float dtv = dts[t][tid];
    float dtu = dtv * us[t][tid];
    sdt += dtv;
    float4 B0 = *(float4*)&Bs[t][0],  B1 = *(float4*)&Bs[t][4];
    float4 B2 = *(float4*)&Bs[t][8],  B3 = *(float4*)&Bs[t][12];
    float Bq[NS] = { B0.x, B0.y, B0.z, B0.w, B1.x, B1.y, B1.z, B1.w,
                     B2.x, B2.y, B2.z, B2.w, B3.x, B3.y, B3.z, B3.w };
#pragma unroll
    for (int n = 0; n < NS; ++n) {
      float a = __expf(dtv * Ad[n]);
      h[n] = fmaf(a, h[n], dtu * Bq[n]);
    }
  }
  const int bd = b * DIN + d;
#pragma unroll
  for (int n = 0; n < NS; ++n) {
    apG[((size_t)c * NS + n) * BDIN + bd] = __expf(Ad[n] * sdt);
    hG [((size_t)c * NS + n) * BDIN + bd] = h[n];
  }
}

// phase 2: in-place hloc -> hinit (exclusive combine over chunks)
__global__ __launch_bounds__(128) void scan_p2(const float* __restrict__ apG,
                                               float* __restrict__ hG)
{
  const int idx = blockIdx.x * 128 + threadIdx.x;     // over NS*BDIN = 32768
  float H = 0.f;
#pragma unroll 16
  for (int c = 0; c < NC; ++c) {
    size_t o = (size_t)c * (NS * BDIN) + idx;
    float ap = apG[o];
    float hl = hG[o];
    hG[o] = H;
    H = fmaf(ap, H, hl);
  }
}

// phase 3: replay from hinit, y = sum_n h*C, fuse D_skip + silu(z); bf16 out
__global__ __launch_bounds__(256) void scan_p3(const float* __restrict__ dt,
                                               const u16* __restrict__ ucb,
                                               const float* __restrict__ xz,
                                               const float* __restrict__ xdbl,
                                               const float* __restrict__ A_log,
                                               const float* __restrict__ D_skip,
                                               const float* __restrict__ hG,
                                               u16* __restrict__ ygb)
{
  __shared__ float dts[CT][256];
  __shared__ float us[CT][256];
  __shared__ float zs[CT][256];
  __shared__ float Bs[CT][NS];
  __shared__ float Cs[CT][NS];
  const int d0 = blockIdx.x * 256, c = blockIdx.y, b = blockIdx.z;
  const int tid = threadIdx.x;
  const int t0 = c * CT;
  for (int i = tid; i < CT * 64; i += 256) {
    int r = i >> 6, col = (i & 63) * 4;
    size_t row = (size_t)(b * LL + t0 + r);
    *(float4*)&dts[r][col] = *(const float4*)&dt[row * DIN + d0 + col];
    ushort4 uv = *(const ushort4*)&ucb[row * DIN + d0 + col];
    float4 uf = { bf2f(uv.x), bf2f(uv.y), bf2f(uv.z), bf2f(uv.w) };
    *(float4*)&us[r][col] = uf;
    *(float4*)&zs[r][col] = *(const float4*)&xz[row * (2 * DIN) + DIN + d0 + col];
  }
  { int r = tid >> 4, n = tid & 15;
    size_t row = (size_t)(b * LL + t0 + r);
    Bs[r][n] = xdbl[row * 64 + 32 + n];
    Cs[r][n] = xdbl[row * 64 + 48 + n]; }
  __syncthreads();
  const int d = d0 + tid;
  const int bd = b * DIN + d;
  float Ad[NS];
#pragma unroll
  for (int n = 0; n < NS; ++n) Ad[n] = -__expf(A_log[d * NS + n]);
  const float Dd = D_skip[d];
  float h[NS];
#pragma unroll
  for (int n = 0; n < NS; ++n) h[n] = hG[((size_t)c * NS + n) * BDIN + bd];
#pragma unroll 2
  for (int t = 0; t < CT; ++t) {
    float dtv = dts[t][tid];
    float ucv = us[t][tid];
    float dtu = dtv * ucv;
    float4 B0 = *(float4*)&Bs[t][0],  B1 = *(float4*)&Bs[t][4];
    float4 B2 = *(float4*)&Bs[t][8],  B3 = *(float4*)&Bs[t][12];
    float4 C0 = *(float4*)&Cs[t][0],  C1 = *(float4*)&Cs[t][4];
    float4 C2 = *(float4*)&Cs[t][8],  C3 = *(float4*)&Cs[t][12];
    float Bq[NS] = { B0.x, B0.y, B0.z, B0.w, B1.x, B1.y, B1.z, B1.w,
                     B2.x, B2.y, B2.z, B2.w, B3.x, B3.y, B3.z, B3.w };
    float Cq[NS] = { C0.x, C0.y, C0.z, C0.w, C1.x, C1.y, C1.z, C1.w,
                     C2.x, C2.y, C2.z, C2.w, C3.x, C3.y, C3.z, C3.w };
    float y = 0.f;
#pragma unroll
    for (int n = 0; n < NS; ++n) {
      float a = __expf(dtv * Ad[n]);
      h[n] = fmaf(a, h[n], dtu * Bq[n]);
      y = fmaf(h[n], Cq[n], y);
    }
    float o = fmaf(ucv, Dd, y) * siluf_(zs[t][tid]);
    ygb[(size_t)(b * LL + t0 + t) * DIN + d0 + tid] = f2bf(o);
  }
}

// ---------------- LN1: r = layernorm(x - m)*g1 + b1, dual fp32+bf16 out ----------------
__global__ __launch_bounds__(256) void ln1_kernel(const float* __restrict__ x,
                                                  const float* __restrict__ m,
                                                  const float* __restrict__ g,
                                                  const float* __restrict__ b,
                                                  float* __restrict__ r,
                                                  u16* __restrict__ rbf)
{
  int row = blockIdx.x;
  int tid = threadIdx.x;
  size_t base = (size_t)row * DD;
  float2 xv = *(const float2*)&x[base + tid * 2];
  float2 mv = *(const float2*)&m[base + tid * 2];
  float v0 = xv.x - mv.x, v1 = xv.y - mv.y;
  float s = v0 + v1, ss = v0 * v0 + v1 * v1;
#pragma unroll
  for (int off = 32; off; off >>= 1) { s += __shfl_down(s, off, 64); ss += __shfl_down(ss, off, 64); }
  __shared__ float sm[8];
  int w = tid >> 6;
  if ((tid & 63) == 0) { sm[w] = s; sm[4 + w] = ss; }
  __syncthreads();
  float S = sm[0] + sm[1] + sm[2] + sm[3];
  float SS = sm[4] + sm[5] + sm[6] + sm[7];
  float mean = S * (1.f / DD);
  float var = SS * (1.f / DD) - mean * mean;
  float rstd = rsqrtf(var + 1e-5f);
  float2 gv = *(const float2*)&g[tid * 2];
  float2 bv = *(const float2*)&b[tid * 2];
  float2 o;
  o.x = (v0 - mean) * rstd * gv.x + bv.x;
  o.y = (v1 - mean) * rstd * gv.y + bv.y;
  *(float2*)&r[base + tid * 2] = o;
  u32 pk = (u32)f2bf(o.x) | ((u32)f2bf(o.y) << 16);
  *(u32*)&rbf[base + tid * 2] = pk;
}

// ---------------- final: out = layernorm(silu(r - ff)) * g2 + b2 + x ----------------
__global__ __launch_bounds__(256) void final_kernel(const float* __restrict__ r,
                                                    const float* __restrict__ ff,
                                                    const float* __restrict__ x,
                                                    const float* __restrict__ g,
                                                    const float* __restrict__ b,
                                                    float* __restrict__ out)
{
  int row = blockIdx.x;
  int tid = threadIdx.x;
  size_t base = (size_t)row * DD;
  float2 rv = *(const float2*)&r[base + tid * 2];
  float2 fv = *(const float2*)&ff[base + tid * 2];
  float v0 = rv.x - fv.x, v1 = rv.y - fv.y;
  v0 = siluf_(v0); v1 = siluf_(v1);
  float s = v0 + v1, ss = v0 * v0 + v1 * v1;
#pragma unroll
  for (int off = 32; off; off >>= 1) { s += __shfl_down(s, off, 64); ss += __shfl_down(ss, off, 64); }
  __shared__ float sm[8];
  int w = tid >> 6;
  if ((tid & 63) == 0) { sm[w] = s; sm[4 + w] = ss; }
  __syncthreads();
  float S = sm[0] + sm[1] + sm[2] + sm[3];
  float SS = sm[4] + sm[5] + sm[6] + sm[7];
  float mean = S * (1.f / DD);
  float var = SS * (1.f / DD) - mean * mean;
  float rstd = rsqrtf(var + 1e-5f);
  float2 gv = *(const float2*)&g[tid * 2];
  float2 bv = *(const float2*)&b[tid * 2];
  float2 xv = *(const float2*)&x[base + tid * 2];
  float2 o;
  o.x = (v0 - mean) * rstd * gv.x + bv.x + xv.x;
  o.y = (v1 - mean) * rstd * gv.y + bv.y + xv.y;
  *(float2*)&out[base + tid * 2] = o;
}

extern "C" void kernel_launch(void* const* d_in, const int* in_sizes, int n_in,
                              void* d_out, int out_size, void* d_ws, size_t ws_size,
                              hipStream_t stream)
{
  const float* x      = (const float*)d_in[0];
  const float* W_in   = (const float*)d_in[1];
  const float* conv_w = (const float*)d_in[2];
  const float* conv_b = (const float*)d_in[3];
  const float* W_xp   = (const float*)d_in[4];
  const float* W_dt   = (const float*)d_in[5];
  const float* b_dt   = (const float*)d_in[6];
  const float* A_log  = (const float*)d_in[7];
  const float* D_skip = (const float*)d_in[8];
  const float* W_out  = (const float*)d_in[9];
  const float* g1     = (const float*)d_in[10];
  const float* b1     = (const float*)d_in[11];
  const float* W_ff1  = (const float*)d_in[12];
  const float* b_ff1  = (const float*)d_in[13];
  const float* W_ff2  = (const float*)d_in[14];
  const float* b_ff2  = (const float*)d_in[15];
  const float* g2     = (const float*)d_in[16];
  const float* b2     = (const float*)d_in[17];
  float* out = (float*)d_out;

  float* ws = (float*)d_ws;
  // fp32 regions (float offsets)
  float* xz   = ws;                     // 4,194,304
  float* apG  = ws + 4194304;           // 2,097,152 (NC*NS*BDIN) — ex-uc region
  float* xdbl = ws + 6291456;           //   131,072
  float* dtb  = ws + 6422528;           // 2,097,152
  u16*   ygb  = (u16*)(ws + 8519680);   // 2,097,152 bf16
  float* mb   = ws + 9568256;           // 1,048,576
  float* rb   = ws + 10616832;          // 1,048,576
  float* big  = ws + 11665408;          // 1,572,864
  u16*   ucb  = (u16*)(ws + 13238272);  // 2,097,152 bf16
  u16*   bWxp = (u16*)(ws + 14286848);  // 65,536 bf16
  // overlays
  u16* bx     = (u16*)mb;               // dead after in_proj
  u16* bW_in  = (u16*)(mb + 524288);
  float* hG   = mb;                     // 2,097,152: mb+rb during scan (both dead then)
  u16* bW_out = (u16*)dtb;              // cast after scan (dtb dead)
  u16* bW_ff1 = (u16*)(dtb + 262144);
  u16* bW_ff2 = (u16*)(dtb + 524288);
  u16* bffh   = (u16*)big;              // post-scan
  u16* brb    = (u16*)(big + 1048576);

  // 1. casts for in_proj / x_proj
  cvt_bf16<<<512, 256, 0, stream>>>(x, bx, ML * DD);
  cvt_bf16<<<512, 256, 0, stream>>>(W_in, bW_in, 2 * DIN * DD);
  cvt_bf16<<<32, 256, 0, stream>>>(W_xp, bWxp, 64 * DIN);
  // 2. in_proj (bf16 MFMA): xz = x @ W_in^T
  gemm_bf16<0, float><<<dim3(16, 16), 256, 0, stream>>>(bx, bW_in, nullptr, xz, ML, 2 * DIN, DD);
  // 3. conv + silu -> ucb (bf16)
  conv_silu<<<(ML * DIN) / 256, 256, 0, stream>>>(xz, conv_w, conv_b, ucb);
  // 4. x_proj (bf16 MFMA)
  xproj_mfma<<<ML / 128, 256, 0, stream>>>(ucb, bWxp, xdbl);
  // 5. dt_proj + softplus
  dtproj_kernel<<<(ML * DIN) / 256, 256, 0, stream>>>(xdbl, W_dt, b_dt, dtb);
  // 6. chunked scan (register-state)
  scan_p1<<<dim3(DIN / 256, NC, BB), 256, 0, stream>>>(dtb, ucb, xdbl, A_log, apG, hG);
  scan_p2<<<(NS * BDIN) / 128, 128, 0, stream>>>(apG, hG);
  scan_p3<<<dim3(DIN / 256, NC, BB), 256, 0, stream>>>(dtb, ucb, xz, xdbl, A_log, D_skip,
                                                       hG, ygb);
  // 7. weight casts (dtb now dead)
  cvt_bf16<<<256, 256, 0, stream>>>(W_out, bW_out, DD * DIN);
  cvt_bf16<<<256, 256, 0, stream>>>(W_ff1, bW_ff1, 2 * DD * DD);
  cvt_bf16<<<256, 256, 0, stream>>>(W_ff2, bW_ff2, DD * DIN);
  // 8. out_proj: mb = yg @ W_out^T  (overwrites hG region — scan done)
  gemm_bf16<0, float><<<dim3(4, 16), 256, 0, stream>>>(ygb, bW_out, nullptr, mb, ML, DD, DIN);
  // 9. LN1 (fp32 + bf16 out)
  ln1_kernel<<<ML, 256, 0, stream>>>(x, mb, g1, b1, rb, brb);
  // 10. ff1 + bias + gelu -> bf16
  gemm_bf16<2, u16><<<dim3(8, 16), 256, 0, stream>>>(brb, bW_ff1, b_ff1, bffh, ML, DIN, DD);
  // 11. ff2 + bias -> mb
  gemm_bf16<1, float><<<dim3(4, 16), 256, 0, stream>>>(bffh, bW_ff2, b_ff2, mb, ML, DD, DIN);
  // 12. final
  final_kernel<<<ML, 256, 0, stream>>>(rb, mb, x, g2, b2, out);
}

// Round 6
// 204.803 us; speedup vs baseline: 4.9850x; 1.0804x over previous
//
#include <hip/hip_runtime.h>
#include <math.h>

#define BB 2
#define LL 1024
#define DD 512
#define DIN 1024      // d_inner
#define NS 16         // d_state
#define RNK 32        // dt_rank
#define ML (BB*LL)    // 2048 rows
#define CT 16         // scan chunk length
#define NC (LL/CT)    // 64 chunks
#define BDIN (BB*DIN) // 2048

typedef unsigned short u16;
typedef unsigned int u32;

__device__ __forceinline__ float sigmoidf_(float v) { return 1.f / (1.f + __expf(-v)); }
__device__ __forceinline__ float siluf_(float v) { return v * sigmoidf_(v); }
__device__ __forceinline__ u16 f2bf(float f) {
  union { float f; u32 u; } c; c.f = f;
  u32 r = c.u + 0x7fffu + ((c.u >> 16) & 1u);
  return (u16)(r >> 16);
}
__device__ __forceinline__ float bf2f(u16 x) {
  union { u32 u; float f; } c; c.u = (u32)x << 16;
  return c.f;
}

// ---------------- fp32 -> bf16 cast (n multiple of 2048) ----------------
__global__ __launch_bounds__(256) void cvt_bf16(const float* __restrict__ in,
                                                u16* __restrict__ out, int n)
{
  int i = (blockIdx.x * 256 + threadIdx.x) * 8;
  if (i >= n) return;
  float4 v0 = *(const float4*)&in[i];
  float4 v1 = *(const float4*)&in[i + 4];
  union { u16 u[8]; uint4 v; } p;
  p.u[0] = f2bf(v0.x); p.u[1] = f2bf(v0.y); p.u[2] = f2bf(v0.z); p.u[3] = f2bf(v0.w);
  p.u[4] = f2bf(v1.x); p.u[5] = f2bf(v1.y); p.u[6] = f2bf(v1.z); p.u[7] = f2bf(v1.w);
  *(uint4*)&out[i] = p.v;
}

// ---------------- bf16 MFMA GEMM: C[M,N] = A[M,K] @ W[N,K]^T ----------------
// EPI: 0 none, 1 +bias, 2 +bias+gelu, 3 +bias+softplus.  OT: float or u16
using bf16x8 = __attribute__((ext_vector_type(8))) short;
using f32x4  = __attribute__((ext_vector_type(4))) float;

template<int EPI, typename OT>
__global__ __launch_bounds__(256) void gemm_bf16(const u16* __restrict__ A,
                                                 const u16* __restrict__ W,
                                                 const float* __restrict__ bias,
                                                 OT* __restrict__ C,
                                                 int M, int N, int K)
{
  __shared__ u16 As[128][40];
  __shared__ u16 Bs[128][40];
  const int bm = blockIdx.y * 128, bn = blockIdx.x * 128;
  const int tid = threadIdx.x;
  const int w = tid >> 6, l = tid & 63;
  const int wr = w >> 1, wc = w & 1;
  const int lr = l & 15, lh = l >> 4;
  const int sr0 = tid >> 2, sc0 = tid & 3;
  f32x4 acc[4][4] = {};
  for (int k0 = 0; k0 < K; k0 += 32) {
    uint4 a0 = *(const uint4*)&A[(size_t)(bm + sr0) * K + k0 + sc0 * 8];
    uint4 a1 = *(const uint4*)&A[(size_t)(bm + sr0 + 64) * K + k0 + sc0 * 8];
    uint4 b0 = *(const uint4*)&W[(size_t)(bn + sr0) * K + k0 + sc0 * 8];
    uint4 b1 = *(const uint4*)&W[(size_t)(bn + sr0 + 64) * K + k0 + sc0 * 8];
    __syncthreads();
    *(uint4*)&As[sr0][sc0 * 8] = a0;
    *(uint4*)&As[sr0 + 64][sc0 * 8] = a1;
    *(uint4*)&Bs[sr0][sc0 * 8] = b0;
    *(uint4*)&Bs[sr0 + 64][sc0 * 8] = b1;
    __syncthreads();
    bf16x8 af[4], bfr[4];
#pragma unroll
    for (int i = 0; i < 4; ++i) af[i]  = *(bf16x8*)&As[wr * 64 + i * 16 + lr][lh * 8];
#pragma unroll
    for (int j = 0; j < 4; ++j) bfr[j] = *(bf16x8*)&Bs[wc * 64 + j * 16 + lr][lh * 8];
#pragma unroll
    for (int i = 0; i < 4; ++i)
#pragma unroll
      for (int j = 0; j < 4; ++j)
        acc[i][j] = __builtin_amdgcn_mfma_f32_16x16x32_bf16(af[i], bfr[j], acc[i][j], 0, 0, 0);
  }
#pragma unroll
  for (int i = 0; i < 4; ++i) {
#pragma unroll
    for (int j = 0; j < 4; ++j) {
      int col = bn + wc * 64 + j * 16 + lr;
      float bv = (EPI >= 1) ? bias[col] : 0.f;
#pragma unroll
      for (int r = 0; r < 4; ++r) {
        int row = bm + wr * 64 + i * 16 + lh * 4 + r;
        float t = acc[i][j][r] + bv;
        if (EPI == 2) t = 0.5f * t * (1.f + erff(t * 0.70710678118654752f));
        if (EPI == 3) t = fmaxf(t, 0.f) + log1pf(__expf(-fabsf(t)));
        if constexpr (sizeof(OT) == 2) C[(size_t)row * N + col] = (OT)f2bf(t);
        else                           C[(size_t)row * N + col] = (OT)t;
      }
    }
  }
}

// ---------------- x_proj via MFMA: xdbl[M,64] = ucb @ Wxb^T (+ bf16 dt_r copy) ----------------
__global__ __launch_bounds__(256) void xproj_mfma(const u16* __restrict__ A,
                                                  const u16* __restrict__ W,
                                                  float* __restrict__ C,
                                                  u16* __restrict__ bdtr)
{
  __shared__ u16 As[128][40];
  __shared__ u16 Bs[64][40];
  const int bm = blockIdx.x * 128;
  const int tid = threadIdx.x;
  const int w = tid >> 6, l = tid & 63;
  const int lr = l & 15, lh = l >> 4;
  const int sr0 = tid >> 2, sc0 = tid & 3;
  f32x4 acc[2][4] = {};
  for (int k0 = 0; k0 < DIN; k0 += 32) {
    uint4 a0 = *(const uint4*)&A[(size_t)(bm + sr0) * DIN + k0 + sc0 * 8];
    uint4 a1 = *(const uint4*)&A[(size_t)(bm + sr0 + 64) * DIN + k0 + sc0 * 8];
    uint4 b0;
    if (sr0 < 64) b0 = *(const uint4*)&W[(size_t)sr0 * DIN + k0 + sc0 * 8];
    __syncthreads();
    *(uint4*)&As[sr0][sc0 * 8] = a0;
    *(uint4*)&As[sr0 + 64][sc0 * 8] = a1;
    if (sr0 < 64) *(uint4*)&Bs[sr0][sc0 * 8] = b0;
    __syncthreads();
    bf16x8 af[2], bfr[4];
#pragma unroll
    for (int i = 0; i < 2; ++i) af[i]  = *(bf16x8*)&As[w * 32 + i * 16 + lr][lh * 8];
#pragma unroll
    for (int j = 0; j < 4; ++j) bfr[j] = *(bf16x8*)&Bs[j * 16 + lr][lh * 8];
#pragma unroll
    for (int i = 0; i < 2; ++i)
#pragma unroll
      for (int j = 0; j < 4; ++j)
        acc[i][j] = __builtin_amdgcn_mfma_f32_16x16x32_bf16(af[i], bfr[j], acc[i][j], 0, 0, 0);
  }
#pragma unroll
  for (int i = 0; i < 2; ++i)
#pragma unroll
    for (int j = 0; j < 4; ++j) {
      int col = j * 16 + lr;
#pragma unroll
      for (int r = 0; r < 4; ++r) {
        int row = bm + w * 32 + i * 16 + lh * 4 + r;
        float v = acc[i][j][r];
        C[(size_t)row * 64 + col] = v;
        if (j < 2) bdtr[(size_t)row * RNK + col] = f2bf(v);   // dt_r (cols 0..31) in bf16
      }
    }
}

// ---------------- depthwise causal conv (K=4) + SiLU -> bf16 only ----------------
__global__ __launch_bounds__(256) void conv_silu(const float* __restrict__ xz,
                                                 const float* __restrict__ conv_w,
                                                 const float* __restrict__ conv_b,
                                                 u16* __restrict__ ucb)
{
  int idx = blockIdx.x * 256 + threadIdx.x;
  int d = idx & (DIN - 1);
  int bl = idx >> 10;
  int l = bl & (LL - 1);
  int b = bl >> 10;
  float acc = conv_b[d];
#pragma unroll
  for (int k = 0; k < 4; ++k) {
    int ls = l - 3 + k;
    float uv = (ls >= 0) ? xz[((size_t)(b * LL + ls)) * (2 * DIN) + d] : 0.f;
    acc = fmaf(uv, conv_w[d * 4 + k], acc);
  }
  ucb[idx] = f2bf(siluf_(acc));
}

// ================= chunked selective scan, register-state design =================
// thread = one d, 16 n-states in VGPRs. state layout: [c][n][b*DIN+d]

__global__ __launch_bounds__(256) void scan_p1(const float* __restrict__ dt,
                                               const u16* __restrict__ ucb,
                                               const float* __restrict__ xdbl,
                                               const float* __restrict__ A_log,
                                               float* __restrict__ apG,
                                               float* __restrict__ hG)
{
  __shared__ float dts[CT][256];
  __shared__ float us[CT][256];
  __shared__ float Bs[CT][NS];
  const int d0 = blockIdx.x * 256, c = blockIdx.y, b = blockIdx.z;
  const int tid = threadIdx.x;
  const int t0 = c * CT;
  for (int i = tid; i < CT * 64; i += 256) {
    int r = i >> 6, col = (i & 63) * 4;
    size_t row = (size_t)(b * LL + t0 + r);
    *(float4*)&dts[r][col] = *(const float4*)&dt[row * DIN + d0 + col];
    ushort4 uv = *(const ushort4*)&ucb[row * DIN + d0 + col];
    float4 uf = { bf2f(uv.x), bf2f(uv.y), bf2f(uv.z), bf2f(uv.w) };
    *(float4*)&us[r][col] = uf;
  }
  { int r = tid >> 4, n = tid & 15;
    Bs[r][n] = xdbl[(size_t)(b * LL + t0 + r) * 64 + 32 + n]; }
  __syncthreads();
  const int d = d0 + tid;
  float Ad[NS];
#pragma unroll
  for (int n = 0; n < NS; ++n) Ad[n] = -__expf(A_log[d * NS + n]);
  float h[NS] = {};
  float sdt = 0.f;
#pragma unroll 4
  for (int t = 0; t < CT; ++t) {
    float dtv = dts[t][tid];
    float dtu = dtv * us[t][tid];
    sdt += dtv;
    float4 B0 = *(float4*)&Bs[t][0],  B1 = *(float4*)&Bs[t][4];
    float4 B2 = *(float4*)&Bs[t][8],  B3 = *(float4*)&Bs[t][12];
    float Bq[NS] = { B0.x, B0.y, B0.z, B0.w, B1.x, B1.y, B1.z, B1.w,
                     B2.x, B2.y, B2.z, B2.w, B3.x, B3.y, B3.z, B3.w };
#pragma unroll
    for (int n = 0; n < NS; ++n) {
      float a = __expf(dtv * Ad[n]);
      h[n] = fmaf(a, h[n], dtu * Bq[n]);
    }
  }
  const int bd = b * DIN + d;
#pragma unroll
  for (int n = 0; n < NS; ++n) {
    apG[((size_t)c * NS + n) * BDIN + bd] = __expf(Ad[n] * sdt);
    hG [((size_t)c * NS + n) * BDIN + bd] = h[n];
  }
}

__global__ __launch_bounds__(128) void scan_p2(const float* __restrict__ apG,
                                               float* __restrict__ hG)
{
  const int idx = blockIdx.x * 128 + threadIdx.x;
  float H = 0.f;
#pragma unroll 16
  for (int c = 0; c < NC; ++c) {
    size_t o = (size_t)c * (NS * BDIN) + idx;
    float ap = apG[o];
    float hl = hG[o];
    hG[o] = H;
    H = fmaf(ap, H, hl);
  }
}

__global__ __launch_bounds__(256) void scan_p3(const float* __restrict__ dt,
                                               const u16* __restrict__ ucb,
                                               const float* __restrict__ xz,
                                               const float* __restrict__ xdbl,
                                               const float* __restrict__ A_log,
                                               const float* __restrict__ D_skip,
                                               const float* __restrict__ hG,
                                               u16* __restrict__ ygb)
{
  __shared__ float dts[CT][256];
  __shared__ float us[CT][256];
  __shared__ float zs[CT][256];
  __shared__ float Bs[CT][NS];
  __shared__ float Cs[CT][NS];
  const int d0 = blockIdx.x * 256, c = blockIdx.y, b = blockIdx.z;
  const int tid = threadIdx.x;
  const int t0 = c * CT;
  for (int i = tid; i < CT * 64; i += 256) {
    int r = i >> 6, col = (i & 63) * 4;
    size_t row = (size_t)(b * LL + t0 + r);
    *(float4*)&dts[r][col] = *(const float4*)&dt[row * DIN + d0 + col];
    ushort4 uv = *(const ushort4*)&ucb[row * DIN + d0 + col];
    float4 uf = { bf2f(uv.x), bf2f(uv.y), bf2f(uv.z), bf2f(uv.w) };
    *(float4*)&us[r][col] = uf;
    *(float4*)&zs[r][col] = *(const float4*)&xz[row * (2 * DIN) + DIN + d0 + col];
  }
  { int r = tid >> 4, n = tid & 15;
    size_t row = (size_t)(b * LL + t0 + r);
    Bs[r][n] = xdbl[row * 64 + 32 + n];
    Cs[r][n] = xdbl[row * 64 + 48 + n]; }
  __syncthreads();
  const int d = d0 + tid;
  const int bd = b * DIN + d;
  float Ad[NS];
#pragma unroll
  for (int n = 0; n < NS; ++n) Ad[n] = -__expf(A_log[d * NS + n]);
  const float Dd = D_skip[d];
  float h[NS];
#pragma unroll
  for (int n = 0; n < NS; ++n) h[n] = hG[((size_t)c * NS + n) * BDIN + bd];
#pragma unroll 2
  for (int t = 0; t < CT; ++t) {
    float dtv = dts[t][tid];
    float ucv = us[t][tid];
    float dtu = dtv * ucv;
    float4 B0 = *(float4*)&Bs[t][0],  B1 = *(float4*)&Bs[t][4];
    float4 B2 = *(float4*)&Bs[t][8],  B3 = *(float4*)&Bs[t][12];
    float4 C0 = *(float4*)&Cs[t][0],  C1 = *(float4*)&Cs[t][4];
    float4 C2 = *(float4*)&Cs[t][8],  C3 = *(float4*)&Cs[t][12];
    float Bq[NS] = { B0.x, B0.y, B0.z, B0.w, B1.x, B1.y, B1.z, B1.w,
                     B2.x, B2.y, B2.z, B2.w, B3.x, B3.y, B3.z, B3.w };
    float Cq[NS] = { C0.x, C0.y, C0.z, C0.w, C1.x, C1.y, C1.z, C1.w,
                     C2.x, C2.y, C2.z, C2.w, C3.x, C3.y, C3.z, C3.w };
    float y = 0.f;
#pragma unroll
    for (int n = 0; n < NS; ++n) {
      float a = __expf(dtv * Ad[n]);
      h[n] = fmaf(a, h[n], dtu * Bq[n]);
      y = fmaf(h[n], Cq[n], y);
    }
    float o = fmaf(ucv, Dd, y) * siluf_(zs[t][tid]);
    ygb[(size_t)(b * LL + t0 + t) * DIN + d0 + tid] = f2bf(o);
  }
}

// ---------------- LN1: r = layernorm(x - m)*g1 + b1, dual fp32+bf16 out ----------------
__global__ __launch_bounds__(256) void ln1_kernel(const float* __restrict__ x,
                                                  const float* __restrict__ m,
                                                  const float* __restrict__ g,
                                                  const float* __restrict__ b,
                                                  float* __restrict__ r,
                                                  u16* __restrict__ rbf)
{
  int row = blockIdx.x;
  int tid = threadIdx.x;
  size_t base = (size_t)row * DD;
  float2 xv = *(const float2*)&x[base + tid * 2];
  float2 mv = *(const float2*)&m[base + tid * 2];
  float v0 = xv.x - mv.x, v1 = xv.y - mv.y;
  float s = v0 + v1, ss = v0 * v0 + v1 * v1;
#pragma unroll
  for (int off = 32; off; off >>= 1) { s += __shfl_down(s, off, 64); ss += __shfl_down(ss, off, 64); }
  __shared__ float sm[8];
  int w = tid >> 6;
  if ((tid & 63) == 0) { sm[w] = s; sm[4 + w] = ss; }
  __syncthreads();
  float S = sm[0] + sm[1] + sm[2] + sm[3];
  float SS = sm[4] + sm[5] + sm[6] + sm[7];
  float mean = S * (1.f / DD);
  float var = SS * (1.f / DD) - mean * mean;
  float rstd = rsqrtf(var + 1e-5f);
  float2 gv = *(const float2*)&g[tid * 2];
  float2 bv = *(const float2*)&b[tid * 2];
  float2 o;
  o.x = (v0 - mean) * rstd * gv.x + bv.x;
  o.y = (v1 - mean) * rstd * gv.y + bv.y;
  *(float2*)&r[base + tid * 2] = o;
  u32 pk = (u32)f2bf(o.x) | ((u32)f2bf(o.y) << 16);
  *(u32*)&rbf[base + tid * 2] = pk;
}

// ---------------- final: out = layernorm(silu(r - ff)) * g2 + b2 + x ----------------
__global__ __launch_bounds__(256) void final_kernel(const float* __restrict__ r,
                                                    const float* __restrict__ ff,
                                                    const float* __restrict__ x,
                                                    const float* __restrict__ g,
                                                    const float* __restrict__ b,
                                                    float* __restrict__ out)
{
  int row = blockIdx.x;
  int tid = threadIdx.x;
  size_t base = (size_t)row * DD;
  float2 rv = *(const float2*)&r[base + tid * 2];
  float2 fv = *(const float2*)&ff[base + tid * 2];
  float v0 = rv.x - fv.x, v1 = rv.y - fv.y;
  v0 = siluf_(v0); v1 = siluf_(v1);
  float s = v0 + v1, ss = v0 * v0 + v1 * v1;
#pragma unroll
  for (int off = 32; off; off >>= 1) { s += __shfl_down(s, off, 64); ss += __shfl_down(ss, off, 64); }
  __shared__ float sm[8];
  int w = tid >> 6;
  if ((tid & 63) == 0) { sm[w] = s; sm[4 + w] = ss; }
  __syncthreads();
  float S = sm[0] + sm[1] + sm[2] + sm[3];
  float SS = sm[4] + sm[5] + sm[6] + sm[7];
  float mean = S * (1.f / DD);
  float var = SS * (1.f / DD) - mean * mean;
  float rstd = rsqrtf(var + 1e-5f);
  float2 gv = *(const float2*)&g[tid * 2];
  float2 bv = *(const float2*)&b[tid * 2];
  float2 xv = *(const float2*)&x[base + tid * 2];
  float2 o;
  o.x = (v0 - mean) * rstd * gv.x + bv.x + xv.x;
  o.y = (v1 - mean) * rstd * gv.y + bv.y + xv.y;
  *(float2*)&out[base + tid * 2] = o;
}

extern "C" void kernel_launch(void* const* d_in, const int* in_sizes, int n_in,
                              void* d_out, int out_size, void* d_ws, size_t ws_size,
                              hipStream_t stream)
{
  const float* x      = (const float*)d_in[0];
  const float* W_in   = (const float*)d_in[1];
  const float* conv_w = (const float*)d_in[2];
  const float* conv_b = (const float*)d_in[3];
  const float* W_xp   = (const float*)d_in[4];
  const float* W_dt   = (const float*)d_in[5];
  const float* b_dt   = (const float*)d_in[6];
  const float* A_log  = (const float*)d_in[7];
  const float* D_skip = (const float*)d_in[8];
  const float* W_out  = (const float*)d_in[9];
  const float* g1     = (const float*)d_in[10];
  const float* b1     = (const float*)d_in[11];
  const float* W_ff1  = (const float*)d_in[12];
  const float* b_ff1  = (const float*)d_in[13];
  const float* W_ff2  = (const float*)d_in[14];
  const float* b_ff2  = (const float*)d_in[15];
  const float* g2     = (const float*)d_in[16];
  const float* b2     = (const float*)d_in[17];
  float* out = (float*)d_out;

  float* ws = (float*)d_ws;
  // fp32 regions (float offsets)
  float* xz   = ws;                     // 4,194,304
  float* apG  = ws + 4194304;           // 2,097,152 (NC*NS*BDIN)
  float* xdbl = ws + 6291456;           //   131,072
  float* dtb  = ws + 6422528;           // 2,097,152
  u16*   ygb  = (u16*)(ws + 8519680);   // 2,097,152 bf16
  float* mb   = ws + 9568256;           // 1,048,576
  float* rb   = ws + 10616832;          // 1,048,576
  float* big  = ws + 11665408;          // 1,572,864
  u16*   ucb  = (u16*)(ws + 13238272);  // 2,097,152 bf16
  u16*   bWxp = (u16*)(ws + 14286848);  // 65,536 bf16
  // overlays
  u16* bx     = (u16*)mb;               // dead after in_proj
  u16* bW_in  = (u16*)(mb + 524288);
  float* hG   = mb;                     // scan states: mb+rb (both dead during scan)
  u16* bW_out = (u16*)dtb;              // cast after scan (dtb dead)
  u16* bW_ff1 = (u16*)(dtb + 262144);
  u16* bW_ff2 = (u16*)(dtb + 524288);
  u16* bdtr   = (u16*)big;              // 65,536 u16 — dt_r bf16 (dead before ff1)
  u16* bW_dt  = (u16*)(big + 32768);    // 32,768 u16
  u16* bffh   = (u16*)big;              // post-scan (bdtr/bW_dt dead by then)
  u16* brb    = (u16*)(big + 1048576);

  // 1. casts for in_proj / x_proj / dt_proj
  cvt_bf16<<<512, 256, 0, stream>>>(x, bx, ML * DD);
  cvt_bf16<<<512, 256, 0, stream>>>(W_in, bW_in, 2 * DIN * DD);
  cvt_bf16<<<32, 256, 0, stream>>>(W_xp, bWxp, 64 * DIN);
  cvt_bf16<<<16, 256, 0, stream>>>(W_dt, bW_dt, DIN * RNK);
  // 2. in_proj (bf16 MFMA): xz = x @ W_in^T
  gemm_bf16<0, float><<<dim3(16, 16), 256, 0, stream>>>(bx, bW_in, nullptr, xz, ML, 2 * DIN, DD);
  // 3. conv + silu -> ucb (bf16)
  conv_silu<<<(ML * DIN) / 256, 256, 0, stream>>>(xz, conv_w, conv_b, ucb);
  // 4. x_proj (bf16 MFMA), also emits bf16 dt_r
  xproj_mfma<<<ML / 128, 256, 0, stream>>>(ucb, bWxp, xdbl, bdtr);
  // 5. dt_proj as MFMA GEMM + softplus epilogue: dtb = softplus(dt_r @ W_dt^T + b_dt)
  gemm_bf16<3, float><<<dim3(DIN / 128, ML / 128), 256, 0, stream>>>(bdtr, bW_dt, b_dt, dtb,
                                                                     ML, DIN, RNK);
  // 6. chunked scan (register-state)
  scan_p1<<<dim3(DIN / 256, NC, BB), 256, 0, stream>>>(dtb, ucb, xdbl, A_log, apG, hG);
  scan_p2<<<(NS * BDIN) / 128, 128, 0, stream>>>(apG, hG);
  scan_p3<<<dim3(DIN / 256, NC, BB), 256, 0, stream>>>(dtb, ucb, xz, xdbl, A_log, D_skip,
                                                       hG, ygb);
  // 7. weight casts (dtb region reuse is safe: bW_out etc. live in dtb, now dead)
  cvt_bf16<<<256, 256, 0, stream>>>(W_out, bW_out, DD * DIN);
  cvt_bf16<<<256, 256, 0, stream>>>(W_ff1, bW_ff1, 2 * DD * DD);
  cvt_bf16<<<256, 256, 0, stream>>>(W_ff2, bW_ff2, DD * DIN);
  // 8. out_proj: mb = yg @ W_out^T  (overwrites hG region — scan done)
  gemm_bf16<0, float><<<dim3(4, 16), 256, 0, stream>>>(ygb, bW_out, nullptr, mb, ML, DD, DIN);
  // 9. LN1 (fp32 + bf16 out)
  ln1_kernel<<<ML, 256, 0, stream>>>(x, mb, g1, b1, rb, brb);
  // 10. ff1 + bias + gelu -> bf16
  gemm_bf16<2, u16><<<dim3(8, 16), 256, 0, stream>>>(brb, bW_ff1, b_ff1, bffh, ML, DIN, DD);
  // 11. ff2 + bias -> mb
  gemm_bf16<1, float><<<dim3(4, 16), 256, 0, stream>>>(bffh, bW_ff2, b_ff2, mb, ML, DD, DIN);
  // 12. final
  final_kernel<<<ML, 256, 0, stream>>>(rb, mb, x, g2, b2, out);
}

// Round 8
// 172.917 us; speedup vs baseline: 5.9042x; 1.1844x over previous
//
#include <hip/hip_runtime.h>
#include <math.h>

#define BB 2
#define LL 1024
#define DD 512
#define DIN 1024      // d_inner
#define NS 16         // d_state
#define RNK 32        // dt_rank
#define ML (BB*LL)    // 2048 rows
#define CT 16         // scan chunk length
#define NC (LL/CT)    // 64 chunks
#define BDIN (BB*DIN) // 2048

typedef unsigned short u16;
typedef unsigned int u32;

__device__ __forceinline__ float sigmoidf_(float v) { return 1.f / (1.f + __expf(-v)); }
__device__ __forceinline__ float siluf_(float v) { return v * sigmoidf_(v); }
__device__ __forceinline__ u16 f2bf(float f) {
  union { float f; u32 u; } c; c.f = f;
  u32 r = c.u + 0x7fffu + ((c.u >> 16) & 1u);
  return (u16)(r >> 16);
}
__device__ __forceinline__ float bf2f(u16 x) {
  union { u32 u; float f; } c; c.u = (u32)x << 16;
  return c.f;
}

// ---------------- fused bf16 cast of x + all weights (one launch) ----------------
// 2048 elems/block. budget: x 512 | W_in 512 | W_xp 32 | W_dt 16 | W_out 256 | W_ff1 256 | W_ff2 256
// (W_in is 2048x512 = 1,048,576 elems -> 512 blocks; R7 wrongly gave it 1024 -> OOB read crash)
__global__ __launch_bounds__(256) void cast_all(const float* __restrict__ x,
                                                const float* __restrict__ Wi,
                                                const float* __restrict__ Wx,
                                                const float* __restrict__ Wd,
                                                const float* __restrict__ Wo,
                                                const float* __restrict__ Wf1,
                                                const float* __restrict__ Wf2,
                                                u16* bx, u16* bWi, u16* bWx, u16* bWd,
                                                u16* bWo, u16* bWf1, u16* bWf2)
{
  int bid = blockIdx.x;
  const float* src; u16* dst; int base;
  if (bid < 512)       { src = x;   dst = bx;   base = 0; }
  else if (bid < 1024) { src = Wi;  dst = bWi;  base = 512; }
  else if (bid < 1056) { src = Wx;  dst = bWx;  base = 1024; }
  else if (bid < 1072) { src = Wd;  dst = bWd;  base = 1056; }
  else if (bid < 1328) { src = Wo;  dst = bWo;  base = 1072; }
  else if (bid < 1584) { src = Wf1; dst = bWf1; base = 1328; }
  else                 { src = Wf2; dst = bWf2; base = 1584; }
  int i = ((bid - base) * 256 + threadIdx.x) * 8;
  float4 v0 = *(const float4*)&src[i];
  float4 v1 = *(const float4*)&src[i + 4];
  union { u16 u[8]; uint4 v; } p;
  p.u[0] = f2bf(v0.x); p.u[1] = f2bf(v0.y); p.u[2] = f2bf(v0.z); p.u[3] = f2bf(v0.w);
  p.u[4] = f2bf(v1.x); p.u[5] = f2bf(v1.y); p.u[6] = f2bf(v1.z); p.u[7] = f2bf(v1.w);
  *(uint4*)&dst[i] = p.v;
}

// ---------------- tiled bf16 MFMA GEMM: C[M,N] = A[M,K] @ W[N,K]^T ----------------
// BM in {64,128}; BN multiple of 16. 4 waves: WR=BM/64 wave-rows, WC=4/WR wave-cols.
// EPI: 0 none, 1 +bias, 2 +bias+gelu, 3 +bias+softplus.  OT: float or u16
using bf16x8 = __attribute__((ext_vector_type(8))) short;
using f32x4  = __attribute__((ext_vector_type(4))) float;

template<int BM, int BN, int EPI, typename OT>
__global__ __launch_bounds__(256) void gemm_t(const u16* __restrict__ A,
                                              const u16* __restrict__ W,
                                              const float* __restrict__ bias,
                                              OT* __restrict__ C,
                                              int M, int N, int K)
{
  constexpr int WR = BM / 64;
  constexpr int WC = 4 / WR;
  constexpr int NW = BN / WC;       // cols per wave
  constexpr int JJ = NW / 16;       // 16-col fragments per wave
  constexpr int RB = BN / 64;       // B row-groups for staging
  __shared__ u16 As[BM][40];        // pad to 40 (80B row): 2-way bank alias = free
  __shared__ u16 Bs[BN][40];
  const int bm = blockIdx.y * BM, bn = blockIdx.x * BN;
  const int tid = threadIdx.x;
  const int w = tid >> 6, l = tid & 63;
  const int wr = w / WC, wc = w % WC;
  const int lr = l & 15, lh = l >> 4;
  const int sr0 = tid >> 2, sc0 = tid & 3;
  f32x4 acc[4][JJ] = {};
  for (int k0 = 0; k0 < K; k0 += 32) {
    uint4 areg[WR], breg[RB];
#pragma unroll
    for (int i = 0; i < WR; ++i)
      areg[i] = *(const uint4*)&A[(size_t)(bm + sr0 + 64 * i) * K + k0 + sc0 * 8];
#pragma unroll
    for (int i = 0; i < RB; ++i)
      breg[i] = *(const uint4*)&W[(size_t)(bn + sr0 + 64 * i) * K + k0 + sc0 * 8];
    __syncthreads();
#pragma unroll
    for (int i = 0; i < WR; ++i) *(uint4*)&As[sr0 + 64 * i][sc0 * 8] = areg[i];
#pragma unroll
    for (int i = 0; i < RB; ++i) *(uint4*)&Bs[sr0 + 64 * i][sc0 * 8] = breg[i];
    __syncthreads();
    bf16x8 af[4], bfr[JJ];
#pragma unroll
    for (int i = 0; i < 4; ++i) af[i]  = *(bf16x8*)&As[wr * 64 + i * 16 + lr][lh * 8];
#pragma unroll
    for (int j = 0; j < JJ; ++j) bfr[j] = *(bf16x8*)&Bs[wc * NW + j * 16 + lr][lh * 8];
#pragma unroll
    for (int i = 0; i < 4; ++i)
#pragma unroll
      for (int j = 0; j < JJ; ++j)
        acc[i][j] = __builtin_amdgcn_mfma_f32_16x16x32_bf16(af[i], bfr[j], acc[i][j], 0, 0, 0);
  }
#pragma unroll
  for (int i = 0; i < 4; ++i) {
#pragma unroll
    for (int j = 0; j < JJ; ++j) {
      int col = bn + wc * NW + j * 16 + lr;
      float bv = (EPI >= 1) ? bias[col] : 0.f;
#pragma unroll
      for (int r = 0; r < 4; ++r) {
        int row = bm + wr * 64 + i * 16 + lh * 4 + r;
        float t = acc[i][j][r] + bv;
        if (EPI == 2) t = 0.5f * t * (1.f + erff(t * 0.70710678118654752f));
        if (EPI == 3) t = fmaxf(t, 0.f) + log1pf(__expf(-fabsf(t)));
        if constexpr (sizeof(OT) == 2) C[(size_t)row * N + col] = (OT)f2bf(t);
        else                           C[(size_t)row * N + col] = (OT)t;
      }
    }
  }
}

// ---------------- x_proj via MFMA: xdbl[M,64] = ucb @ Wxb^T (+ bf16 dt_r copy) ----------------
__global__ __launch_bounds__(256) void xproj_mfma(const u16* __restrict__ A,
                                                  const u16* __restrict__ W,
                                                  float* __restrict__ C,
                                                  u16* __restrict__ bdtr)
{
  __shared__ u16 As[128][40];
  __shared__ u16 Bs[64][40];
  const int bm = blockIdx.x * 128;
  const int tid = threadIdx.x;
  const int w = tid >> 6, l = tid & 63;
  const int lr = l & 15, lh = l >> 4;
  const int sr0 = tid >> 2, sc0 = tid & 3;
  f32x4 acc[2][4] = {};
  for (int k0 = 0; k0 < DIN; k0 += 32) {
    uint4 a0 = *(const uint4*)&A[(size_t)(bm + sr0) * DIN + k0 + sc0 * 8];
    uint4 a1 = *(const uint4*)&A[(size_t)(bm + sr0 + 64) * DIN + k0 + sc0 * 8];
    uint4 b0;
    if (sr0 < 64) b0 = *(const uint4*)&W[(size_t)sr0 * DIN + k0 + sc0 * 8];
    __syncthreads();
    *(uint4*)&As[sr0][sc0 * 8] = a0;
    *(uint4*)&As[sr0 + 64][sc0 * 8] = a1;
    if (sr0 < 64) *(uint4*)&Bs[sr0][sc0 * 8] = b0;
    __syncthreads();
    bf16x8 af[2], bfr[4];
#pragma unroll
    for (int i = 0; i < 2; ++i) af[i]  = *(bf16x8*)&As[w * 32 + i * 16 + lr][lh * 8];
#pragma unroll
    for (int j = 0; j < 4; ++j) bfr[j] = *(bf16x8*)&Bs[j * 16 + lr][lh * 8];
#pragma unroll
    for (int i = 0; i < 2; ++i)
#pragma unroll
      for (int j = 0; j < 4; ++j)
        acc[i][j] = __builtin_amdgcn_mfma_f32_16x16x32_bf16(af[i], bfr[j], acc[i][j], 0, 0, 0);
  }
#pragma unroll
  for (int i = 0; i < 2; ++i)
#pragma unroll
    for (int j = 0; j < 4; ++j) {
      int col = j * 16 + lr;
#pragma unroll
      for (int r = 0; r < 4; ++r) {
        int row = bm + w * 32 + i * 16 + lh * 4 + r;
        float v = acc[i][j][r];
        C[(size_t)row * 64 + col] = v;
        if (j < 2) bdtr[(size_t)row * RNK + col] = f2bf(v);   // dt_r cols 0..31
      }
    }
}

// ---------------- depthwise causal conv (K=4) + SiLU -> bf16 ----------------
__global__ __launch_bounds__(256) void conv_silu(const float* __restrict__ xz,
                                                 const float* __restrict__ conv_w,
                                                 const float* __restrict__ conv_b,
                                                 u16* __restrict__ ucb)
{
  int idx = blockIdx.x * 256 + threadIdx.x;
  int d = idx & (DIN - 1);
  int bl = idx >> 10;
  int l = bl & (LL - 1);
  int b = bl >> 10;
  float acc = conv_b[d];
#pragma unroll
  for (int k = 0; k < 4; ++k) {
    int ls = l - 3 + k;
    float uv = (ls >= 0) ? xz[((size_t)(b * LL + ls)) * (2 * DIN) + d] : 0.f;
    acc = fmaf(uv, conv_w[d * 4 + k], acc);
  }
  ucb[idx] = f2bf(siluf_(acc));
}

// ================= chunked selective scan, register-state design =================
// thread = one d, 16 n-states in VGPRs. state layout: [c][n][b*DIN+d]

__global__ __launch_bounds__(256) void scan_p1(const float* __restrict__ dt,
                                               const u16* __restrict__ ucb,
                                               const float* __restrict__ xdbl,
                                               const float* __restrict__ A_log,
                                               float* __restrict__ apG,
                                               float* __restrict__ hG)
{
  __shared__ float dts[CT][256];
  __shared__ float us[CT][256];
  __shared__ float Bs[CT][NS];
  const int d0 = blockIdx.x * 256, c = blockIdx.y, b = blockIdx.z;
  const int tid = threadIdx.x;
  const int t0 = c * CT;
  for (int i = tid; i < CT * 64; i += 256) {
    int r = i >> 6, col = (i & 63) * 4;
    size_t row = (size_t)(b * LL + t0 + r);
    *(float4*)&dts[r][col] = *(const float4*)&dt[row * DIN + d0 + col];
    ushort4 uv = *(const ushort4*)&ucb[row * DIN + d0 + col];
    float4 uf = { bf2f(uv.x), bf2f(uv.y), bf2f(uv.z), bf2f(uv.w) };
    *(float4*)&us[r][col] = uf;
  }
  { int r = tid >> 4, n = tid & 15;
    Bs[r][n] = xdbl[(size_t)(b * LL + t0 + r) * 64 + 32 + n]; }
  __syncthreads();
  const int d = d0 + tid;
  float Ad[NS];
#pragma unroll
  for (int n = 0; n < NS; ++n) Ad[n] = -__expf(A_log[d * NS + n]);
  float h[NS] = {};
  float sdt = 0.f;
#pragma unroll 4
  for (int t = 0; t < CT; ++t) {
    float dtv = dts[t][tid];
    float dtu = dtv * us[t][tid];
    sdt += dtv;
    float4 B0 = *(float4*)&Bs[t][0],  B1 = *(float4*)&Bs[t][4];
    float4 B2 = *(float4*)&Bs[t][8],  B3 = *(float4*)&Bs[t][12];
    float Bq[NS] = { B0.x, B0.y, B0.z, B0.w, B1.x, B1.y, B1.z, B1.w,
                     B2.x, B2.y, B2.z, B2.w, B3.x, B3.y, B3.z, B3.w };
#pragma unroll
    for (int n = 0; n < NS; ++n) {
      float a = __expf(dtv * Ad[n]);
      h[n] = fmaf(a, h[n], dtu * Bq[n]);
    }
  }
  const int bd = b * DIN + d;
#pragma unroll
  for (int n = 0; n < NS; ++n) {
    apG[((size_t)c * NS + n) * BDIN + bd] = __expf(Ad[n] * sdt);
    hG [((size_t)c * NS + n) * BDIN + bd] = h[n];
  }
}

__global__ __launch_bounds__(128) void scan_p2(const float* __restrict__ apG,
                                               float* __restrict__ hG)
{
  const int idx = blockIdx.x * 128 + threadIdx.x;
  float H = 0.f;
#pragma unroll 16
  for (int c = 0; c < NC; ++c) {
    size_t o = (size_t)c * (NS * BDIN) + idx;
    float ap = apG[o];
    float hl = hG[o];
    hG[o] = H;
    H = fmaf(ap, H, hl);
  }
}

__global__ __launch_bounds__(256) void scan_p3(const float* __restrict__ dt,
                                               const u16* __restrict__ ucb,
                                               const float* __restrict__ xz,
                                               const float* __restrict__ xdbl,
                                               const float* __restrict__ A_log,
                                               const float* __restrict__ D_skip,
                                               const float* __restrict__ hG,
                                               u16* __restrict__ ygb)
{
  __shared__ float dts[CT][256];
  __shared__ float us[CT][256];
  __shared__ float zs[CT][256];
  __shared__ float Bs[CT][NS];
  __shared__ float Cs[CT][NS];
  const int d0 = blockIdx.x * 256, c = blockIdx.y, b = blockIdx.z;
  const int tid = threadIdx.x;
  const int t0 = c * CT;
  for (int i = tid; i < CT * 64; i += 256) {
    int r = i >> 6, col = (i & 63) * 4;
    size_t row = (size_t)(b * LL + t0 + r);
    *(float4*)&dts[r][col] = *(const float4*)&dt[row * DIN + d0 + col];
    ushort4 uv = *(const ushort4*)&ucb[row * DIN + d0 + col];
    float4 uf = { bf2f(uv.x), bf2f(uv.y), bf2f(uv.z), bf2f(uv.w) };
    *(float4*)&us[r][col] = uf;
    *(float4*)&zs[r][col] = *(const float4*)&xz[row * (2 * DIN) + DIN + d0 + col];
  }
  { int r = tid >> 4, n = tid & 15;
    size_t row = (size_t)(b * LL + t0 + r);
    Bs[r][n] = xdbl[row * 64 + 32 + n];
    Cs[r][n] = xdbl[row * 64 + 48 + n]; }
  __syncthreads();
  const int d = d0 + tid;
  const int bd = b * DIN + d;
  float Ad[NS];
#pragma unroll
  for (int n = 0; n < NS; ++n) Ad[n] = -__expf(A_log[d * NS + n]);
  const float Dd = D_skip[d];
  float h[NS];
#pragma unroll
  for (int n = 0; n < NS; ++n) h[n] = hG[((size_t)c * NS + n) * BDIN + bd];
#pragma unroll 2
  for (int t = 0; t < CT; ++t) {
    float dtv = dts[t][tid];
    float ucv = us[t][tid];
    float dtu = dtv * ucv;
    float4 B0 = *(float4*)&Bs[t][0],  B1 = *(float4*)&Bs[t][4];
    float4 B2 = *(float4*)&Bs[t][8],  B3 = *(float4*)&Bs[t][12];
    float4 C0 = *(float4*)&Cs[t][0],  C1 = *(float4*)&Cs[t][4];
    float4 C2 = *(float4*)&Cs[t][8],  C3 = *(float4*)&Cs[t][12];
    float Bq[NS] = { B0.x, B0.y, B0.z, B0.w, B1.x, B1.y, B1.z, B1.w,
                     B2.x, B2.y, B2.z, B2.w, B3.x, B3.y, B3.z, B3.w };
    float Cq[NS] = { C0.x, C0.y, C0.z, C0.w, C1.x, C1.y, C1.z, C1.w,
                     C2.x, C2.y, C2.z, C2.w, C3.x, C3.y, C3.z, C3.w };
    float y = 0.f;
#pragma unroll
    for (int n = 0; n < NS; ++n) {
      float a = __expf(dtv * Ad[n]);
      h[n] = fmaf(a, h[n], dtu * Bq[n]);
      y = fmaf(h[n], Cq[n], y);
    }
    float o = fmaf(ucv, Dd, y) * siluf_(zs[t][tid]);
    ygb[(size_t)(b * LL + t0 + t) * DIN + d0 + tid] = f2bf(o);
  }
}

// ---------------- LN1: r = layernorm(x - m)*g1 + b1, dual fp32+bf16 out ----------------
__global__ __launch_bounds__(256) void ln1_kernel(const float* __restrict__ x,
                                                  const float* __restrict__ m,
                                                  const float* __restrict__ g,
                                                  const float* __restrict__ b,
                                                  float* __restrict__ r,
                                                  u16* __restrict__ rbf)
{
  int row = blockIdx.x;
  int tid = threadIdx.x;
  size_t base = (size_t)row * DD;
  float2 xv = *(const float2*)&x[base + tid * 2];
  float2 mv = *(const float2*)&m[base + tid * 2];
  float v0 = xv.x - mv.x, v1 = xv.y - mv.y;
  float s = v0 + v1, ss = v0 * v0 + v1 * v1;
#pragma unroll
  for (int off = 32; off; off >>= 1) { s += __shfl_down(s, off, 64); ss += __shfl_down(ss, off, 64); }
  __shared__ float sm[8];
  int w = tid >> 6;
  if ((tid & 63) == 0) { sm[w] = s; sm[4 + w] = ss; }
  __syncthreads();
  float S = sm[0] + sm[1] + sm[2] + sm[3];
  float SS = sm[4] + sm[5] + sm[6] + sm[7];
  float mean = S * (1.f / DD);
  float var = SS * (1.f / DD) - mean * mean;
  float rstd = rsqrtf(var + 1e-5f);
  float2 gv = *(const float2*)&g[tid * 2];
  float2 bv = *(const float2*)&b[tid * 2];
  float2 o;
  o.x = (v0 - mean) * rstd * gv.x + bv.x;
  o.y = (v1 - mean) * rstd * gv.y + bv.y;
  *(float2*)&r[base + tid * 2] = o;
  u32 pk = (u32)f2bf(o.x) | ((u32)f2bf(o.y) << 16);
  *(u32*)&rbf[base + tid * 2] = pk;
}

// ---------------- final: out = layernorm(silu(r - ff)) * g2 + b2 + x ----------------
__global__ __launch_bounds__(256) void final_kernel(const float* __restrict__ r,
                                                    const float* __restrict__ ff,
                                                    const float* __restrict__ x,
                                                    const float* __restrict__ g,
                                                    const float* __restrict__ b,
                                                    float* __restrict__ out)
{
  int row = blockIdx.x;
  int tid = threadIdx.x;
  size_t base = (size_t)row * DD;
  float2 rv = *(const float2*)&r[base + tid * 2];
  float2 fv = *(const float2*)&ff[base + tid * 2];
  float v0 = rv.x - fv.x, v1 = rv.y - fv.y;
  v0 = siluf_(v0); v1 = siluf_(v1);
  float s = v0 + v1, ss = v0 * v0 + v1 * v1;
#pragma unroll
  for (int off = 32; off; off >>= 1) { s += __shfl_down(s, off, 64); ss += __shfl_down(ss, off, 64); }
  __shared__ float sm[8];
  int w = tid >> 6;
  if ((tid & 63) == 0) { sm[w] = s; sm[4 + w] = ss; }
  __syncthreads();
  float S = sm[0] + sm[1] + sm[2] + sm[3];
  float SS = sm[4] + sm[5] + sm[6] + sm[7];
  float mean = S * (1.f / DD);
  float var = SS * (1.f / DD) - mean * mean;
  float rstd = rsqrtf(var + 1e-5f);
  float2 gv = *(const float2*)&g[tid * 2];
  float2 bv = *(const float2*)&b[tid * 2];
  float2 xv = *(const float2*)&x[base + tid * 2];
  float2 o;
  o.x = (v0 - mean) * rstd * gv.x + bv.x + xv.x;
  o.y = (v1 - mean) * rstd * gv.y + bv.y + xv.y;
  *(float2*)&out[base + tid * 2] = o;
}

extern "C" void kernel_launch(void* const* d_in, const int* in_sizes, int n_in,
                              void* d_out, int out_size, void* d_ws, size_t ws_size,
                              hipStream_t stream)
{
  const float* x      = (const float*)d_in[0];
  const float* W_in   = (const float*)d_in[1];
  const float* conv_w = (const float*)d_in[2];
  const float* conv_b = (const float*)d_in[3];
  const float* W_xp   = (const float*)d_in[4];
  const float* W_dt   = (const float*)d_in[5];
  const float* b_dt   = (const float*)d_in[6];
  const float* A_log  = (const float*)d_in[7];
  const float* D_skip = (const float*)d_in[8];
  const float* W_out  = (const float*)d_in[9];
  const float* g1     = (const float*)d_in[10];
  const float* b1     = (const float*)d_in[11];
  const float* W_ff1  = (const float*)d_in[12];
  const float* b_ff1  = (const float*)d_in[13];
  const float* W_ff2  = (const float*)d_in[14];
  const float* b_ff2  = (const float*)d_in[15];
  const float* g2     = (const float*)d_in[16];
  const float* b2     = (const float*)d_in[17];
  float* out = (float*)d_out;

  // linear layout, ~75 MB total
  float* ws = (float*)d_ws;
  float* xz     = ws;                       // 4,194,304
  float* xdbl   = ws + 4194304;             //   131,072
  float* dtb    = ws + 4325376;             // 2,097,152
  float* apG    = ws + 6422528;             // 2,097,152
  float* hG     = ws + 8519680;             // 2,097,152
  float* mb     = ws + 10616832;            // 1,048,576
  float* rb     = ws + 11665408;            // 1,048,576
  u16*   bffh   = (u16*)(ws + 12713984);    // 2,097,152 u16
  u16*   ygb    = (u16*)(ws + 13762560);    // 2,097,152 u16
  u16*   ucb    = (u16*)(ws + 14811136);    // 2,097,152 u16
  u16*   brb    = (u16*)(ws + 15859712);    // 1,048,576 u16
  u16*   bdtr   = (u16*)(ws + 16384000);    //    65,536 u16
  u16*   bx     = (u16*)(ws + 16416768);    // 1,048,576 u16
  u16*   bW_in  = (u16*)(ws + 16941056);    // 1,048,576 u16
  u16*   bWxp   = (u16*)(ws + 17989632);    //    65,536 u16
  u16*   bW_dt  = (u16*)(ws + 18022400);    //    32,768 u16
  u16*   bW_out = (u16*)(ws + 18038784);    //   524,288 u16
  u16*   bW_ff1 = (u16*)(ws + 18300928);    //   524,288 u16
  u16*   bW_ff2 = (u16*)(ws + 18563072);    //   524,288 u16

  // 1. fused casts (x + 6 weights)
  cast_all<<<1840, 256, 0, stream>>>(x, W_in, W_xp, W_dt, W_out, W_ff1, W_ff2,
                                     bx, bW_in, bWxp, bW_dt, bW_out, bW_ff1, bW_ff2);
  // 2. in_proj: xz = x @ W_in^T   (BM=128, BN=64 -> 512 blocks, 2/CU)
  gemm_t<128, 64, 0, float><<<dim3(2 * DIN / 64, ML / 128), 256, 0, stream>>>(
      bx, bW_in, nullptr, xz, ML, 2 * DIN, DD);
  // 3. conv + silu -> ucb (bf16)
  conv_silu<<<(ML * DIN) / 256, 256, 0, stream>>>(xz, conv_w, conv_b, ucb);
  // 4. x_proj (bf16 MFMA), also emits bf16 dt_r
  xproj_mfma<<<ML / 128, 256, 0, stream>>>(ucb, bWxp, xdbl, bdtr);
  // 5. dt_proj as MFMA GEMM + softplus epilogue
  gemm_t<128, 64, 3, float><<<dim3(DIN / 64, ML / 128), 256, 0, stream>>>(
      bdtr, bW_dt, b_dt, dtb, ML, DIN, RNK);
  // 6. chunked scan (register-state)
  scan_p1<<<dim3(DIN / 256, NC, BB), 256, 0, stream>>>(dtb, ucb, xdbl, A_log, apG, hG);
  scan_p2<<<(NS * BDIN) / 128, 128, 0, stream>>>(apG, hG);
  scan_p3<<<dim3(DIN / 256, NC, BB), 256, 0, stream>>>(dtb, ucb, xz, xdbl, A_log, D_skip,
                                                       hG, ygb);
  // 7. out_proj: mb = yg @ W_out^T  (BM=64, BN=64 -> 256 blocks)
  gemm_t<64, 64, 0, float><<<dim3(DD / 64, ML / 64), 256, 0, stream>>>(
      ygb, bW_out, nullptr, mb, ML, DD, DIN);
  // 8. LN1 (fp32 + bf16 out)
  ln1_kernel<<<ML, 256, 0, stream>>>(x, mb, g1, b1, rb, brb);
  // 9. ff1 + bias + gelu -> bf16  (BM=128, BN=64 -> 256 blocks)
  gemm_t<128, 64, 2, u16><<<dim3(DIN / 64, ML / 128), 256, 0, stream>>>(
      brb, bW_ff1, b_ff1, bffh, ML, DIN, DD);
  // 10. ff2 + bias -> mb  (BM=64, BN=64 -> 256 blocks)
  gemm_t<64, 64, 1, float><<<dim3(DD / 64, ML / 64), 256, 0, stream>>>(
      bffh, bW_ff2, b_ff2, mb, ML, DD, DIN);
  // 11. final
  final_kernel<<<ML, 256, 0, stream>>>(rb, mb, x, g2, b2, out);
}